// Round 4
// baseline (5647.789 us; speedup 1.0000x reference)
//
#include <hip/hip_runtime.h>
#include <stdint.h>

// ---------------- problem constants ----------------
#define B_     1024
#define F_     512
#define H_     1024
#define S_     8
#define BOX_   12
#define MAXB_  64
#define MAXSY_ 64
#define L_     126
#define STK_   3
#define NCYC_  42

typedef unsigned short u16;
typedef unsigned int   u32;
typedef unsigned long long u64;
typedef __attribute__((ext_vector_type(8))) short sh8;   // 8 bf16 (4 VGPRs)
typedef __attribute__((ext_vector_type(4))) float f4;    // MFMA accumulator

#define MFMA16(a,b,c) __builtin_amdgcn_mfma_f32_16x16x32_bf16((a),(b),(c),0,0,0)

// ---------------- ws layout (bytes) ----------------
constexpr size_t PL_HF = (size_t)H_ * F_ * 2;      // 1 MB  (Wd, Wsd planes)
constexpr size_t PL_FH = (size_t)F_ * H_ * 2;      // 1 MB  (Wl, Wr, Wsf planes)
constexpr size_t PL_SS = 16384;                    // S*H*2
constexpr size_t PL_BX = 16384;                    // BOX*F*2=12288, padded
constexpr size_t O_WdHi  = 4096;
constexpr size_t O_WdLo  = O_WdHi  + PL_HF;
constexpr size_t O_WsdHi = O_WdLo  + PL_HF;
constexpr size_t O_WsdLo = O_WsdHi + PL_HF;
constexpr size_t O_WlHi  = O_WsdLo + PL_HF;
constexpr size_t O_WlLo  = O_WlHi  + PL_FH;
constexpr size_t O_WrHi  = O_WlLo  + PL_FH;
constexpr size_t O_WrLo  = O_WrHi  + PL_FH;
constexpr size_t O_WsfHi = O_WrLo  + PL_FH;
constexpr size_t O_WsfLo = O_WsfHi + PL_FH;
constexpr size_t O_WssHi = O_WsfLo + PL_FH;
constexpr size_t O_WssLo = O_WssHi + PL_SS;
constexpr size_t O_WbxHi = O_WssLo + PL_SS;
constexpr size_t O_WbxLo = O_WbxHi + PL_BX;
constexpr size_t SZ_STK  = (size_t)B_ * STK_ * F_ * 2;   // 3 MB per plane
constexpr size_t O_SHi   = O_WbxLo + PL_BX;
constexpr size_t O_SLo   = O_SHi   + SZ_STK;
constexpr size_t SZ_H    = (size_t)B_ * H_ * 2;          // 2 MB per plane
constexpr size_t O_HAHi  = O_SLo   + SZ_STK;
constexpr size_t O_HALo  = O_HAHi  + SZ_H;
constexpr size_t O_HSHi  = O_HALo  + SZ_H;
constexpr size_t O_HSLo  = O_HSHi  + SZ_H;
constexpr size_t SZ_FB   = (size_t)B_ * 512 * 2;         // 1 MB per plane
constexpr size_t O_FB0Hi = O_HSLo  + SZ_H;
constexpr size_t O_FB0Lo = O_FB0Hi + SZ_FB;
constexpr size_t O_FB1Hi = O_FB0Lo + SZ_FB;
constexpr size_t O_FB1Lo = O_FB1Hi + SZ_FB;
constexpr size_t WS_NEED = O_FB1Lo + SZ_FB;              // ~28.2 MB
constexpr size_t O_FLAG  = 2048;                         // nonuni flag (int)

// ---------------- numeric helpers ----------------
__device__ __forceinline__ float bf2float(u16 h) {
    union { u32 u; float f; } v; v.u = ((u32)h) << 16; return v.f;
}
__device__ __forceinline__ u16 bfhi_of(float f) {           // RNE fp32->bf16
    union { float f; u32 u; } v; v.f = f;
    u32 u = v.u;
    return (u16)((u + 0x7fffu + ((u >> 16) & 1u)) >> 16);
}
__device__ __forceinline__ void split2(float x, u16& hi, u16& lo) {
    hi = bfhi_of(x);
    lo = bfhi_of(x - bf2float(hi));
}

// ---------------- device-coherent memory ops ----------------
__device__ __forceinline__ void cstore2(u16* p, u16 v) {
    asm volatile("global_store_short %0, %1, off sc0 sc1"
                 :: "v"(p), "v"((u32)v) : "memory");
}
__device__ __forceinline__ void vdrain() {
    asm volatile("s_waitcnt vmcnt(0)" ::: "memory");
}

// ---------------- prep: split weights + input stacks; detect pattern ----------------
__device__ void split_range(const float* __restrict__ s, u16* hi, u16* lo,
                            int n, int t0, int stride) {
    for (int i = t0; i < n; i += stride) {
        float v = s[i];
        u16 h = bfhi_of(v);
        hi[i] = h;
        lo[i] = bfhi_of(v - bf2float(h));
    }
}

__global__ void grass_prep(const float* __restrict__ X, const int* __restrict__ ops,
                           const float* __restrict__ Wd, const float* __restrict__ Wl,
                           const float* __restrict__ Wr, const float* __restrict__ Wsd,
                           const float* __restrict__ Wsf, const float* __restrict__ Wss,
                           const float* __restrict__ Wbox, char* __restrict__ ws)
{
    const int t0 = blockIdx.x * blockDim.x + threadIdx.x;
    const int st = gridDim.x * blockDim.x;
    split_range(Wd,  (u16*)(ws + O_WdHi),  (u16*)(ws + O_WdLo),  H_ * F_, t0, st);
    split_range(Wsd, (u16*)(ws + O_WsdHi), (u16*)(ws + O_WsdLo), H_ * F_, t0, st);
    split_range(Wl,  (u16*)(ws + O_WlHi),  (u16*)(ws + O_WlLo),  F_ * H_, t0, st);
    split_range(Wr,  (u16*)(ws + O_WrHi),  (u16*)(ws + O_WrLo),  F_ * H_, t0, st);
    split_range(Wsf, (u16*)(ws + O_WsfHi), (u16*)(ws + O_WsfLo), F_ * H_, t0, st);
    split_range(Wss, (u16*)(ws + O_WssHi), (u16*)(ws + O_WssLo), S_ * H_, t0, st);
    split_range(Wbox,(u16*)(ws + O_WbxHi), (u16*)(ws + O_WbxLo), BOX_ * F_, t0, st);
    u16* SHi = (u16*)(ws + O_SHi);
    u16* SLo = (u16*)(ws + O_SLo);
    for (int i = t0; i < B_ * F_; i += st) {
        int e = i >> 9, k = i & (F_ - 1);
        float v = X[i];
        u16 h = bfhi_of(v);
        size_t off = (size_t)e * STK_ * F_ + k;     // slot 0
        SHi[off] = h;
        SLo[off] = bfhi_of(v - bf2float(h));
    }
    // pattern check: stored order expects {0,2,1}[t%3]
    int* flag = (int*)(ws + O_FLAG);
    for (int i = t0; i < B_ * L_; i += st) {
        int t = i % L_;
        int tm = t % 3;
        int expect = (tm == 0) ? 0 : ((tm == 1) ? 2 : 1);
        if (ops[i] != expect) {
            __hip_atomic_store(flag, 1, __ATOMIC_RELAXED, __HIP_MEMORY_SCOPE_AGENT);
            break;
        }
    }
}

// -------- group barrier: fence-FREE. All exchange traffic is device-coherent;
// each wave drains vmcnt before s_barrier, then one relaxed agent atomic. --------
__device__ __forceinline__ void gbar(int* bar, int target) {
    vdrain();
    __syncthreads();
    if (threadIdx.x == 0) {
        __hip_atomic_fetch_add(bar, 1, __ATOMIC_RELAXED, __HIP_MEMORY_SCOPE_AGENT);
        while (__hip_atomic_load(bar, __ATOMIC_RELAXED, __HIP_MEMORY_SCOPE_AGENT) < target)
            __builtin_amdgcn_s_sleep(2);
    }
    __syncthreads();
}
__device__ __forceinline__ void gwait(int* ctr, int target) {
    if (threadIdx.x == 0) {
        while (__hip_atomic_load(ctr, __ATOMIC_RELAXED, __HIP_MEMORY_SCOPE_AGENT) < target)
            __builtin_amdgcn_s_sleep(2);
    }
    __syncthreads();
}

// ---------------- bulk activation staging (256-thread blocks, legacy) ----------------
__device__ __forceinline__ void stageA(u16* __restrict__ lds,
    const u16* __restrict__ AHi, const u16* __restrict__ ALo,
    const int* __restrict__ aOff, int kbase, int tid)
{
    const int wv = tid >> 6, lane = tid & 63;
    const int kk = kbase + lane * 8;
    int off[16];
#pragma unroll
    for (int i = 0; i < 16; ++i) off[i] = aOff[i * 4 + wv] + kk;
    u64 v[64];
#pragma unroll
    for (int i = 0; i < 16; ++i) {
        const u64* s = (const u64*)(AHi + off[i]);
        v[2 * i]     = __hip_atomic_load(s,     __ATOMIC_RELAXED, __HIP_MEMORY_SCOPE_AGENT);
        v[2 * i + 1] = __hip_atomic_load(s + 1, __ATOMIC_RELAXED, __HIP_MEMORY_SCOPE_AGENT);
    }
#pragma unroll
    for (int i = 0; i < 16; ++i) {
        const u64* s = (const u64*)(ALo + off[i]);
        v[32 + 2 * i] = __hip_atomic_load(s,     __ATOMIC_RELAXED, __HIP_MEMORY_SCOPE_AGENT);
        v[33 + 2 * i] = __hip_atomic_load(s + 1, __ATOMIC_RELAXED, __HIP_MEMORY_SCOPE_AGENT);
    }
#pragma unroll
    for (int i = 0; i < 16; ++i) {
        const int m = i * 4 + wv;
        u16* d = lds + m * 512 + ((lane * 8) ^ ((m & 7) << 3));
        ((u64*)d)[0] = v[2 * i];
        ((u64*)d)[1] = v[2 * i + 1];
        u64* d2 = (u64*)(d + 32768);
        d2[0] = v[32 + 2 * i];
        d2[1] = v[33 + 2 * i];
    }
}

// ---------------- bulk activation staging (512-thread blocks, pipe) ----------------
__device__ __forceinline__ void stageA512(u16* __restrict__ lds,
    const u16* __restrict__ AHi, const u16* __restrict__ ALo,
    const int* __restrict__ aOff, int kbase, int tid)
{
    const int wv = tid >> 6, lane = tid & 63;    // wv 0..7
    const int kk = kbase + lane * 8;
    int off[8];
#pragma unroll
    for (int i = 0; i < 8; ++i) off[i] = aOff[i * 8 + wv] + kk;
    u64 v[32];
#pragma unroll
    for (int i = 0; i < 8; ++i) {
        const u64* s = (const u64*)(AHi + off[i]);
        v[2 * i]     = __hip_atomic_load(s,     __ATOMIC_RELAXED, __HIP_MEMORY_SCOPE_AGENT);
        v[2 * i + 1] = __hip_atomic_load(s + 1, __ATOMIC_RELAXED, __HIP_MEMORY_SCOPE_AGENT);
    }
#pragma unroll
    for (int i = 0; i < 8; ++i) {
        const u64* s = (const u64*)(ALo + off[i]);
        v[16 + 2 * i] = __hip_atomic_load(s,     __ATOMIC_RELAXED, __HIP_MEMORY_SCOPE_AGENT);
        v[17 + 2 * i] = __hip_atomic_load(s + 1, __ATOMIC_RELAXED, __HIP_MEMORY_SCOPE_AGENT);
    }
#pragma unroll
    for (int i = 0; i < 8; ++i) {
        const int m = i * 8 + wv;
        u16* d = lds + m * 512 + ((lane * 8) ^ ((m & 7) << 3));
        ((u64*)d)[0] = v[2 * i];
        ((u64*)d)[1] = v[2 * i + 1];
        u64* d2 = (u64*)(d + 32768);
        d2[0] = v[16 + 2 * i];
        d2[1] = v[17 + 2 * i];
    }
}

// ---------------- 64x64 split-bf16 k-loop over one staged 512-col panel ----------
// wv4 in 0..3 selects the 32x32 output quadrant.
__device__ __forceinline__ void kloop64(const u16* __restrict__ lds,
    const u16* __restrict__ WHi, const u16* __restrict__ WLo,
    int nRow0, int Kw, int kofs, f4 c[2][2], int lane, int wv4)
{
    const int quad = lane >> 4, mr = lane & 15;
    const int mh = wv4 & 1, nh = (wv4 >> 1) & 1;
    const int m0 = (mh * 2) * 16 + mr, m1 = m0 + 16;
    const int n0 = nRow0 + (nh * 2) * 16 + mr, n1 = n0 + 16;
    const u16* b0h = WHi + (size_t)n0 * Kw + kofs;
    const u16* b1h = WHi + (size_t)n1 * Kw + kofs;
    const u16* b0l = WLo + (size_t)n0 * Kw + kofs;
    const u16* b1l = WLo + (size_t)n1 * Kw + kofs;
    const int sw = (m0 & 7) << 3;
    const u16* A0h = lds + m0 * 512;
    const u16* A1h = lds + m1 * 512;
#pragma unroll 2
    for (int kb = 0; kb < 512; kb += 64) {
        const int k0 = kb + quad * 8, k1 = k0 + 32;
        const int x0 = k0 ^ sw, x1 = k1 ^ sw;
        sh8 B0H0 = *(const sh8*)(b0h + k0), B1H0 = *(const sh8*)(b1h + k0);
        sh8 B0L0 = *(const sh8*)(b0l + k0), B1L0 = *(const sh8*)(b1l + k0);
        sh8 B0H1 = *(const sh8*)(b0h + k1), B1H1 = *(const sh8*)(b1h + k1);
        sh8 B0L1 = *(const sh8*)(b0l + k1), B1L1 = *(const sh8*)(b1l + k1);
        sh8 A0H0 = *(const sh8*)(A0h + x0);
        sh8 A1H0 = *(const sh8*)(A1h + x0);
        sh8 A0L0 = *(const sh8*)(A0h + 32768 + x0);
        sh8 A1L0 = *(const sh8*)(A1h + 32768 + x0);
        sh8 A0H1 = *(const sh8*)(A0h + x1);
        sh8 A1H1 = *(const sh8*)(A1h + x1);
        sh8 A0L1 = *(const sh8*)(A0h + 32768 + x1);
        sh8 A1L1 = *(const sh8*)(A1h + 32768 + x1);
        c[0][0]=MFMA16(A0H0,B0H0,c[0][0]); c[0][1]=MFMA16(A0H0,B1H0,c[0][1]);
        c[1][0]=MFMA16(A1H0,B0H0,c[1][0]); c[1][1]=MFMA16(A1H0,B1H0,c[1][1]);
        c[0][0]=MFMA16(A0H0,B0L0,c[0][0]); c[0][1]=MFMA16(A0H0,B1L0,c[0][1]);
        c[1][0]=MFMA16(A1H0,B0L0,c[1][0]); c[1][1]=MFMA16(A1H0,B1L0,c[1][1]);
        c[0][0]=MFMA16(A0L0,B0H0,c[0][0]); c[0][1]=MFMA16(A0L0,B1H0,c[0][1]);
        c[1][0]=MFMA16(A1L0,B0H0,c[1][0]); c[1][1]=MFMA16(A1L0,B1H0,c[1][1]);
        c[0][0]=MFMA16(A0H1,B0H1,c[0][0]); c[0][1]=MFMA16(A0H1,B1H1,c[0][1]);
        c[1][0]=MFMA16(A1H1,B0H1,c[1][0]); c[1][1]=MFMA16(A1H1,B1H1,c[1][1]);
        c[0][0]=MFMA16(A0H1,B0L1,c[0][0]); c[0][1]=MFMA16(A0H1,B1L1,c[0][1]);
        c[1][0]=MFMA16(A1H1,B0L1,c[1][0]); c[1][1]=MFMA16(A1H1,B1L1,c[1][1]);
        c[0][0]=MFMA16(A0L1,B0H1,c[0][0]); c[0][1]=MFMA16(A0L1,B1H1,c[0][1]);
        c[1][0]=MFMA16(A1L1,B0H1,c[1][0]); c[1][1]=MFMA16(A1L1,B1H1,c[1][1]);
    }
}

// 64 x (<=16): wave wv (0..3) owns rows wv*16..+16.
__device__ __forceinline__ void kloop16(const u16* __restrict__ lds,
    const u16* __restrict__ WHi, const u16* __restrict__ WLo,
    int nValid, int Kw, int kofs, f4& c, int lane, int wv)
{
    const int quad = lane >> 4, mr = lane & 15;
    const int m = wv * 16 + mr;
    const int sm = (m & 7) << 3;
    const u16* Am = lds + m * 512;
    const bool nb = (mr < nValid);
    const u16* bh = WHi + (size_t)mr * Kw + kofs;
    const u16* bl = WLo + (size_t)mr * Kw + kofs;
#pragma unroll 2
    for (int kb = 0; kb < 512; kb += 64) {
        const int k0 = kb + quad * 8, k1 = k0 + 32;
        const int x0 = k0 ^ sm, x1 = k1 ^ sm;
        sh8 bH0 = {0,0,0,0,0,0,0,0}, bL0 = {0,0,0,0,0,0,0,0};
        sh8 bH1 = {0,0,0,0,0,0,0,0}, bL1 = {0,0,0,0,0,0,0,0};
        if (nb) {
            bH0 = *(const sh8*)(bh + k0); bL0 = *(const sh8*)(bl + k0);
            bH1 = *(const sh8*)(bh + k1); bL1 = *(const sh8*)(bl + k1);
        }
        sh8 aH0 = *(const sh8*)(Am + x0);
        sh8 aL0 = *(const sh8*)(Am + 32768 + x0);
        sh8 aH1 = *(const sh8*)(Am + x1);
        sh8 aL1 = *(const sh8*)(Am + 32768 + x1);
        c = MFMA16(aH0, bH0, c);
        c = MFMA16(aH0, bL0, c);
        c = MFMA16(aL0, bH0, c);
        c = MFMA16(aH1, bH1, c);
        c = MFMA16(aH1, bL1, c);
        c = MFMA16(aL1, bH1, c);
    }
}

__device__ __forceinline__ void zacc(f4 c[2][2]) {
    f4 z = {0.f, 0.f, 0.f, 0.f};
    c[0][0] = z; c[0][1] = z; c[1][0] = z; c[1][1] = z;
}

// legacy: stage + k-loop (256-thread blocks)
__device__ __forceinline__ void gemmK(u16* __restrict__ Ab,
    const u16* __restrict__ AHi, const u16* __restrict__ ALo, const int* __restrict__ aOff,
    const u16* __restrict__ WHi, const u16* __restrict__ WLo, int nRow0, int Kw,
    f4 c[2][2], int tid, int lane, int wv)
{
    zacc(c);
    for (int h = 0; h < Kw; h += 512) {
        __syncthreads();
        stageA(Ab, AHi, ALo, aOff, h, tid);
        __syncthreads();
        kloop64(Ab, WHi, WLo, nRow0, Kw, h, c, lane, wv);
    }
}
__device__ __forceinline__ void gemmK16(u16* __restrict__ Ab,
    const u16* __restrict__ AHi, const u16* __restrict__ ALo, const int* __restrict__ aOff,
    const u16* __restrict__ WHi, const u16* __restrict__ WLo, int nValid, int Kw,
    f4& c, int tid, int lane, int wv)
{
    f4 z = {0.f, 0.f, 0.f, 0.f};
    c = z;
    for (int h = 0; h < Kw; h += 512) {
        __syncthreads();
        stageA(Ab, AHi, ALo, aOff, h, tid);
        __syncthreads();
        kloop16(Ab, WHi, WLo, nValid, Kw, h, c, lane, wv);
    }
}

// pipe: 256-col block tile = per-wave 128-col pipeline off one shared panel
__device__ __forceinline__ void pipe_gemm256(u16* __restrict__ Ab,
    const u16* __restrict__ AHi, const u16* __restrict__ ALo, const int* __restrict__ aOff,
    const u16* __restrict__ WHi, const u16* __restrict__ WLo, int colBlock, int Kw,
    f4 cA[2][2], f4 cB[2][2], int tid, int lane, int wv4, int half)
{
    zacc(cA); zacc(cB);
    const int c0 = colBlock + half * 128;
    for (int h = 0; h < Kw; h += 512) {
        __syncthreads();
        stageA512(Ab, AHi, ALo, aOff, h, tid);
        __syncthreads();
        kloop64(Ab, WHi, WLo, c0,      Kw, h, cA, lane, wv4);
        kloop64(Ab, WHi, WLo, c0 + 64, Kw, h, cB, lane, wv4);
    }
}

// ---------------- epilogues (C/D map: col=lane&15, row=(lane>>4)*4+reg) ----------
__device__ __forceinline__ void ep_h(const f4 c[2][2], const float* __restrict__ bias,
                                     int colBase, int e0, u16* DHi, u16* DLo,
                                     int lane, int wv4)
{
    const int quad = lane >> 4, mr = lane & 15;
    const int mh = wv4 & 1, nh = (wv4 >> 1) & 1;
#pragma unroll
    for (int mi = 0; mi < 2; ++mi)
#pragma unroll
    for (int ni = 0; ni < 2; ++ni)
#pragma unroll
    for (int r = 0; r < 4; ++r) {
        int mm = (mh * 2 + mi) * 16 + quad * 4 + r;
        int nn = (nh * 2 + ni) * 16 + mr;
        float v = tanhf(c[mi][ni][r] + bias[colBase + nn]);
        u16 hi, lo; split2(v, hi, lo);
        size_t off = (size_t)(e0 + mm) * H_ + colBase + nn;
        cstore2(DHi + off, hi);
        cstore2(DLo + off, lo);
    }
}

__device__ __forceinline__ void ep_slot(const f4 c[2][2], const float* __restrict__ bias,
                                        int colBase, int slot, int e0,
                                        u16* SHi, u16* SLo, int lane, int wv4)
{
    const int quad = lane >> 4, mr = lane & 15;
    const int mh = wv4 & 1, nh = (wv4 >> 1) & 1;
#pragma unroll
    for (int mi = 0; mi < 2; ++mi)
#pragma unroll
    for (int ni = 0; ni < 2; ++ni)
#pragma unroll
    for (int r = 0; r < 4; ++r) {
        int mm = (mh * 2 + mi) * 16 + quad * 4 + r;
        int nn = (nh * 2 + ni) * 16 + mr;
        float v = tanhf(c[mi][ni][r] + bias[colBase + nn]);
        u16 hi, lo; split2(v, hi, lo);
        size_t off = ((size_t)(e0 + mm) * STK_ + slot) * F_ + colBase + nn;
        cstore2(SHi + off, hi);
        cstore2(SLo + off, lo);
    }
}

__device__ __forceinline__ void ep_fb(const f4 c[2][2], const float* __restrict__ bias,
                                      int colBase, int e0, u16* FHi, u16* FLo,
                                      int lane, int wv4)
{
    const int quad = lane >> 4, mr = lane & 15;
    const int mh = wv4 & 1, nh = (wv4 >> 1) & 1;
#pragma unroll
    for (int mi = 0; mi < 2; ++mi)
#pragma unroll
    for (int ni = 0; ni < 2; ++ni)
#pragma unroll
    for (int r = 0; r < 4; ++r) {
        int mm = (mh * 2 + mi) * 16 + quad * 4 + r;
        int nn = (nh * 2 + ni) * 16 + mr;
        float v = tanhf(c[mi][ni][r] + bias[colBase + nn]);
        u16 hi, lo; split2(v, hi, lo);
        size_t off = (size_t)(e0 + mm) * 512 + colBase + nn;
        cstore2(FHi + off, hi);
        cstore2(FLo + off, lo);
    }
}

__device__ __forceinline__ void ep_stack(const f4 c[2][2], const float* __restrict__ bias,
                                         int colBase, int opSel, bool useRi, int tix, int e0,
                                         const unsigned char* opsL, const int* spA,
                                         u16* SHi, u16* SLo, int lane, int wv)
{
    const int quad = lane >> 4, mr = lane & 15;
    const int mh = wv & 1, nh = (wv >> 1) & 1;
#pragma unroll
    for (int mi = 0; mi < 2; ++mi)
#pragma unroll
    for (int ni = 0; ni < 2; ++ni)
#pragma unroll
    for (int r = 0; r < 4; ++r) {
        int mm = (mh * 2 + mi) * 16 + quad * 4 + r;
        int nn = (nh * 2 + ni) * 16 + mr;
        if (opsL[mm * L_ + tix] != opSel) continue;
        int sp = spA[mm];
        int slot = useRi ? sp : sp - 1;
        slot = slot < 0 ? 0 : (slot > STK_ - 1 ? STK_ - 1 : slot);
        float v = tanhf(c[mi][ni][r] + bias[colBase + nn]);
        u16 hi, lo; split2(v, hi, lo);
        size_t off = ((size_t)(e0 + mm) * STK_ + slot) * F_ + colBase + nn;
        cstore2(SHi + off, hi);
        cstore2(SLo + off, lo);
    }
}

__device__ __forceinline__ void ep_small(const f4& c, const float* __restrict__ bias,
                                         int nValid, int opSel, int tix, int e0,
                                         const unsigned char* opsL, const int* eCnt, const int* eTot,
                                         float* __restrict__ outBase, int rowStride, int ncols,
                                         int lane, int wv)
{
    const int nn = lane & 15;
    if (nn >= nValid) return;
#pragma unroll
    for (int r = 0; r < 4; ++r) {
        int mm = wv * 16 + (lane >> 4) * 4 + r;
        if (opsL[mm * L_ + tix] != opSel) continue;
        int slot = eTot[mm] - 1 - eCnt[mm];
        if (slot < 0 || slot >= 64) continue;
        float v = tanhf(c[r] + bias[nn]);
        outBase[(size_t)(e0 + mm) * rowStride + slot * ncols + nn] = v;
    }
}

__device__ __forceinline__ void ep_small_u(const f4& c, const float* __restrict__ bias,
                                           int nValid, int slot, int e0,
                                           float* __restrict__ outBase, int rowStride, int ncols,
                                           int lane, int wv)
{
    const int nn = lane & 15;
    if (nn >= nValid) return;
#pragma unroll
    for (int r = 0; r < 4; ++r) {
        int mm = wv * 16 + (lane >> 4) * 4 + r;
        outBase[(size_t)(e0 + mm) * rowStride + slot * ncols + nn] = tanhf(c[r] + bias[nn]);
    }
}

// ---------------- pipe kernel: 16 groups x (4 chain + 4 side) x 512 threads ----------
// __launch_bounds__(512, 1): LDS already pins 1 block/CU; the 1 here keeps the
// full 256-VGPR/wave budget (round-3's (512,2) capped VGPR at 128 -> scratch
// spills in stageA512/kloop64, 1.8x regression). 8 waves/block = 2 waves/SIMD.
__global__ __launch_bounds__(512, 1) void grass_pipe(
    const float* __restrict__ bd, const float* __restrict__ bl, const float* __restrict__ br,
    const float* __restrict__ bsd, const float* __restrict__ bsf, const float* __restrict__ bss,
    const float* __restrict__ bbox,
    char* __restrict__ ws, float* __restrict__ out)
{
    if (__hip_atomic_load((int*)(ws + O_FLAG), __ATOMIC_RELAXED, __HIP_MEMORY_SCOPE_AGENT))
        return;   // non-uniform program: legacy kernel handles it

    const int tid  = threadIdx.x;
    const int lane = tid & 63, wv = tid >> 6;   // wv 0..7
    const int wv4  = wv & 3, half = wv >> 2;
    const int gid  = blockIdx.x >> 3;           // group (64 batch rows)
    const int j    = blockIdx.x & 7;            // 0..3 chain, 4..7 side
    const int e0   = gid * 64;

    const u16* WdHi  = (const u16*)(ws + O_WdHi);
    const u16* WdLo  = (const u16*)(ws + O_WdLo);
    const u16* WsdHi = (const u16*)(ws + O_WsdHi);
    const u16* WsdLo = (const u16*)(ws + O_WsdLo);
    const u16* WlHi  = (const u16*)(ws + O_WlHi);
    const u16* WlLo  = (const u16*)(ws + O_WlLo);
    const u16* WrHi  = (const u16*)(ws + O_WrHi);
    const u16* WrLo  = (const u16*)(ws + O_WrLo);
    const u16* WsfHi = (const u16*)(ws + O_WsfHi);
    const u16* WsfLo = (const u16*)(ws + O_WsfLo);
    const u16* WssHi = (const u16*)(ws + O_WssHi);
    const u16* WssLo = (const u16*)(ws + O_WssLo);
    const u16* WbxHi = (const u16*)(ws + O_WbxHi);
    const u16* WbxLo = (const u16*)(ws + O_WbxLo);
    u16* SHi  = (u16*)(ws + O_SHi);
    u16* SLo  = (u16*)(ws + O_SLo);
    u16* HAHi = (u16*)(ws + O_HAHi);
    u16* HALo = (u16*)(ws + O_HALo);
    u16* HSHi = (u16*)(ws + O_HSHi);
    u16* HSLo = (u16*)(ws + O_HSLo);
    u16* FB0Hi = (u16*)(ws + O_FB0Hi);
    u16* FB0Lo = (u16*)(ws + O_FB0Lo);
    u16* FB1Hi = (u16*)(ws + O_FB1Hi);
    u16* FB1Lo = (u16*)(ws + O_FB1Lo);
    int* cbar = (int*)ws + gid * 32;        // 4 chain blocks
    int* sbar = (int*)ws + gid * 32 + 1;    // 4 side blocks

    float* outB = out;
    float* outS = out + (size_t)B_ * MAXB_ * BOX_;

    __shared__ u16 Abuf[2 * 64 * 512];      // 128 KB shared A panel
    __shared__ int aS0[64], aR1[64], aR2[64], aHH[64], aFB[64];

    if (tid < 64) {
        aS0[tid] = ((e0 + tid) * STK_ + 0) * F_;
        aR1[tid] = ((e0 + tid) * STK_ + 1) * F_;
        aR2[tid] = ((e0 + tid) * STK_ + 2) * F_;
        aHH[tid] = (e0 + tid) * H_;
        aFB[tid] = (e0 + tid) * 512;
    }
    __syncthreads();

    f4 cA[2][2], cB[2][2];
    f4 cs;

    if (j < 4) {
        // ===== chain: op1 only =====
        for (int cyc = 0; cyc < NCYC_; ++cyc) {
            // p1: HA = tanh(Wd @ slot0 + bd), block cols j*256
            pipe_gemm256(Abuf, SHi, SLo, aS0, WdHi, WdLo, j * 256, F_, cA, cB, tid, lane, wv4, half);
            ep_h(cA, bd, j * 256 + half * 128,      e0, HAHi, HALo, lane, wv4);
            ep_h(cB, bd, j * 256 + half * 128 + 64, e0, HAHi, HALo, lane, wv4);
            gbar(cbar, 4 * (2 * cyc + 1));
            // p2: l -> slot0 (j<2), r -> rotating slot (j>=2)
            if (j < 2) {
                pipe_gemm256(Abuf, HAHi, HALo, aHH, WlHi, WlLo, j * 256, H_, cA, cB, tid, lane, wv4, half);
                ep_slot(cA, bl, j * 256 + half * 128,      0, e0, SHi, SLo, lane, wv4);
                ep_slot(cB, bl, j * 256 + half * 128 + 64, 0, e0, SHi, SLo, lane, wv4);
            } else {
                const int rs = 1 + (cyc & 1);
                pipe_gemm256(Abuf, HAHi, HALo, aHH, WrHi, WrLo, (j - 2) * 256, H_, cA, cB, tid, lane, wv4, half);
                if (cyc >= 2) gwait(sbar, 4 * (2 * (cyc - 2) + 1));  // r-slot WAR vs side(cyc-2)
                ep_slot(cA, br, (j - 2) * 256 + half * 128,      rs, e0, SHi, SLo, lane, wv4);
                ep_slot(cB, br, (j - 2) * 256 + half * 128 + 64, rs, e0, SHi, SLo, lane, wv4);
            }
            gbar(cbar, 4 * (2 * cyc + 2));
        }
    } else {
        // ===== side: op2 + op0, lagging the chain =====
        const int role = j - 4;
        for (int cyc = 0; cyc < NCYC_; ++cyc) {
            gwait(cbar, 4 * (2 * cyc + 2));            // r(cyc) ready
            const int* aR = (cyc & 1) ? aR2 : aR1;
            // p1: HS = tanh(Wsd @ r + bsd)
            pipe_gemm256(Abuf, SHi, SLo, aR, WsdHi, WsdLo, role * 256, F_, cA, cB, tid, lane, wv4, half);
            ep_h(cA, bsd, role * 256 + half * 128,      e0, HSHi, HSLo, lane, wv4);
            ep_h(cB, bsd, role * 256 + half * 128 + 64, e0, HSHi, HSLo, lane, wv4);
            gbar(sbar, 4 * (2 * cyc + 1));
            // p2: f (roles 0,1), sym + box (role 2), idle (role 3)
            if (role < 2) {
                u16* FH = (cyc & 1) ? FB1Hi : FB0Hi;
                u16* FL = (cyc & 1) ? FB1Lo : FB0Lo;
                pipe_gemm256(Abuf, HSHi, HSLo, aHH, WsfHi, WsfLo, role * 256, H_, cA, cB, tid, lane, wv4, half);
                ep_fb(cA, bsf, role * 256 + half * 128,      e0, FH, FL, lane, wv4);
                ep_fb(cB, bsf, role * 256 + half * 128 + 64, e0, FH, FL, lane, wv4);
            } else if (role == 2) {
                // sym: s = tanh(Wss @ HS + bss)
                f4 z = {0.f, 0.f, 0.f, 0.f}; cs = z;
                for (int h = 0; h < H_; h += 512) {
                    __syncthreads();
                    stageA512(Abuf, HSHi, HSLo, aHH, h, tid);
                    __syncthreads();
                    if (wv < 4) kloop16(Abuf, WssHi, WssLo, S_, H_, h, cs, lane, wv);
                }
                if (wv < 4)
                    ep_small_u(cs, bss, S_, NCYC_ - 1 - cyc, e0, outS, MAXSY_ * S_, S_, lane, wv);
                // box(cyc-1) from FB[(cyc-1)&1]
                if (cyc >= 1) {
                    const u16* FH = ((cyc - 1) & 1) ? FB1Hi : FB0Hi;
                    const u16* FL = ((cyc - 1) & 1) ? FB1Lo : FB0Lo;
                    __syncthreads();
                    stageA512(Abuf, FH, FL, aFB, 0, tid);
                    __syncthreads();
                    if (wv < 4) {
                        f4 z2 = {0.f, 0.f, 0.f, 0.f}; cs = z2;
                        kloop16(Abuf, WbxHi, WbxLo, BOX_, 512, 0, cs, lane, wv);
                        ep_small_u(cs, bbox, BOX_, NCYC_ - (cyc - 1) - 1, e0, outB, MAXB_ * BOX_, BOX_, lane, wv);
                    }
                }
            }
            gbar(sbar, 4 * (2 * cyc + 2));
        }
        if (role == 2) {   // final box(41): f(41) guarded by last sbar
            const u16* FH = ((NCYC_ - 1) & 1) ? FB1Hi : FB0Hi;
            const u16* FL = ((NCYC_ - 1) & 1) ? FB1Lo : FB0Lo;
            __syncthreads();
            stageA512(Abuf, FH, FL, aFB, 0, tid);
            __syncthreads();
            if (wv < 4) {
                f4 z = {0.f, 0.f, 0.f, 0.f}; cs = z;
                kloop16(Abuf, WbxHi, WbxLo, BOX_, 512, 0, cs, lane, wv);
                ep_small_u(cs, bbox, BOX_, 0, e0, outB, MAXB_ * BOX_, BOX_, lane, wv);
            }
        }
    }
}

// ---------------- legacy general kernel (non-uniform programs) ----------------
__global__ __launch_bounds__(256, 2) void grass_legacy(
    const int* __restrict__ ops,
    const float* __restrict__ bd, const float* __restrict__ bl, const float* __restrict__ br,
    const float* __restrict__ bsd, const float* __restrict__ bsf, const float* __restrict__ bss,
    const float* __restrict__ bbox,
    char* __restrict__ ws, float* __restrict__ out)
{
    if (!__hip_atomic_load((int*)(ws + O_FLAG), __ATOMIC_RELAXED, __HIP_MEMORY_SCOPE_AGENT))
        return;   // uniform program: pipe kernel already did the work

    const int tid  = threadIdx.x;
    const int lane = tid & 63, wv = tid >> 6;
    const int gid  = blockIdx.x >> 4;
    const int j    = blockIdx.x & 15;
    const int e0   = gid * 64;

    const u16* WdHi  = (const u16*)(ws + O_WdHi);
    const u16* WdLo  = (const u16*)(ws + O_WdLo);
    const u16* WsdHi = (const u16*)(ws + O_WsdHi);
    const u16* WsdLo = (const u16*)(ws + O_WsdLo);
    const u16* WlHi  = (const u16*)(ws + O_WlHi);
    const u16* WlLo  = (const u16*)(ws + O_WlLo);
    const u16* WrHi  = (const u16*)(ws + O_WrHi);
    const u16* WrLo  = (const u16*)(ws + O_WrLo);
    const u16* WsfHi = (const u16*)(ws + O_WsfHi);
    const u16* WsfLo = (const u16*)(ws + O_WsfLo);
    const u16* WssHi = (const u16*)(ws + O_WssHi);
    const u16* WssLo = (const u16*)(ws + O_WssLo);
    const u16* WbxHi = (const u16*)(ws + O_WbxHi);
    const u16* WbxLo = (const u16*)(ws + O_WbxLo);
    u16* SHi  = (u16*)(ws + O_SHi);
    u16* SLo  = (u16*)(ws + O_SLo);
    u16* HAHi = (u16*)(ws + O_HAHi);
    u16* HALo = (u16*)(ws + O_HALo);
    u16* HSHi = (u16*)(ws + O_HSHi);
    u16* HSLo = (u16*)(ws + O_HSLo);
    int* bar = (int*)ws + gid * 32 + 2;   // distinct from pipe counters

    float* outB = out;
    float* outS = out + (size_t)B_ * MAXB_ * BOX_;

    __shared__ u16 Abuf[2 * 64 * 512];
    __shared__ unsigned char opsL[64 * L_];
    __shared__ int spA[64], beA[64], seA[64], beF[64], seF[64];
    __shared__ int aStk[64], aHH[64];
    __shared__ int sInfo[2];

    for (int idx = tid; idx < 64 * L_; idx += 256) {
        int e = idx / L_, t = idx - e * L_;
        opsL[idx] = (unsigned char)ops[(size_t)(e0 + e) * L_ + t];
    }
    __syncthreads();
    if (tid < 64) {
        spA[tid] = 1; beA[tid] = 0; seA[tid] = 0;
        int cb = 0, cs2 = 0;
        for (int t = 0; t < L_; ++t) {
            int o = opsL[tid * L_ + t];
            cb += (o == 0); cs2 += (o == 2);
        }
        beF[tid] = cb; seF[tid] = cs2;
        aHH[tid]  = (e0 + tid) * H_;
        aStk[tid] = ((e0 + tid) * STK_ + 0) * F_;
    }
    __syncthreads();

    int epoch = 0;
    f4 c[2][2];
    f4 cs;

    for (int step = 0; step < L_; ++step) {
        const int tix = L_ - 1 - step;
        if (wv == 0) {
            int o  = opsL[lane * L_ + tix];
            int sp = spA[lane];
            unsigned long long bo = __ballot(o  == opsL[0 * L_ + tix]);
            unsigned long long bs = __ballot(sp == spA[0]);
            if (lane == 0) {
                sInfo[0] = o;
                sInfo[1] = (bo == ~0ull && bs == ~0ull) ? 1 : 0;
            }
        }
        __syncthreads();
        const int opU = sInfo[0], uni = sInfo[1];

        if (uni) {
            if (opU == 1) {
                gemmK(Abuf, SHi, SLo, aStk, WdHi, WdLo, j * 64, F_, c, tid, lane, wv);
                ep_h(c, bd, j * 64, e0, HAHi, HALo, lane, wv);
                ++epoch; gbar(bar, 16 * epoch);
                {
                    const u16* W2H = (j < 8) ? WlHi : WrHi;
                    const u16* W2L = (j < 8) ? WlLo : WrLo;
                    const float* b2 = (j < 8) ? bl : br;
                    gemmK(Abuf, HAHi, HALo, aHH, W2H, W2L, (j & 7) * 64, H_, c, tid, lane, wv);
                    ep_stack(c, b2, (j & 7) * 64, 1, j >= 8, tix, e0, opsL, spA, SHi, SLo, lane, wv);
                }
                ++epoch; gbar(bar, 16 * epoch);
            } else if (opU == 2) {
                gemmK(Abuf, SHi, SLo, aStk, WsdHi, WsdLo, j * 64, F_, c, tid, lane, wv);
                ep_h(c, bsd, j * 64, e0, HAHi, HALo, lane, wv);
                ++epoch; gbar(bar, 16 * epoch);
                if (j < 8) {
                    gemmK(Abuf, HAHi, HALo, aHH, WsfHi, WsfLo, j * 64, H_, c, tid, lane, wv);
                    ep_stack(c, bsf, j * 64, 2, false, tix, e0, opsL, spA, SHi, SLo, lane, wv);
                } else if (j == 8) {
                    gemmK16(Abuf, HAHi, HALo, aHH, WssHi, WssLo, S_, H_, cs, tid, lane, wv);
                    ep_small(cs, bss, S_, 2, tix, e0, opsL, seA, seF, outS, MAXSY_ * S_, S_, lane, wv);
                }
                ++epoch; gbar(bar, 16 * epoch);
            } else {
                if (j == 0) {
                    gemmK16(Abuf, SHi, SLo, aStk, WbxHi, WbxLo, BOX_, F_, cs, tid, lane, wv);
                    ep_small(cs, bbox, BOX_, 0, tix, e0, opsL, beA, beF, outB, MAXB_ * BOX_, BOX_, lane, wv);
                }
            }
        } else {
            gemmK(Abuf, SHi, SLo, aStk, WdHi, WdLo, j * 64, F_, c, tid, lane, wv);
            ep_h(c, bd, j * 64, e0, HAHi, HALo, lane, wv);
            gemmK(Abuf, SHi, SLo, aStk, WsdHi, WsdLo, j * 64, F_, c, tid, lane, wv);
            ep_h(c, bsd, j * 64, e0, HSHi, HSLo, lane, wv);
            if (j == 0) {
                gemmK16(Abuf, SHi, SLo, aStk, WbxHi, WbxLo, BOX_, F_, cs, tid, lane, wv);
                ep_small(cs, bbox, BOX_, 0, tix, e0, opsL, beA, beF, outB, MAXB_ * BOX_, BOX_, lane, wv);
            }
            ++epoch; gbar(bar, 16 * epoch);
            if (j < 8) {
                gemmK(Abuf, HAHi, HALo, aHH, WlHi, WlLo, j * 64, H_, c, tid, lane, wv);
                ep_stack(c, bl, j * 64, 1, false, tix, e0, opsL, spA, SHi, SLo, lane, wv);
                gemmK(Abuf, HSHi, HSLo, aHH, WsfHi, WsfLo, j * 64, H_, c, tid, lane, wv);
                ep_stack(c, bsf, j * 64, 2, false, tix, e0, opsL, spA, SHi, SLo, lane, wv);
            } else {
                gemmK(Abuf, HAHi, HALo, aHH, WrHi, WrLo, (j - 8) * 64, H_, c, tid, lane, wv);
                ep_stack(c, br, (j & 7) * 64, 1, true, tix, e0, opsL, spA, SHi, SLo, lane, wv);
                if (j == 8) {
                    gemmK16(Abuf, HAHi, HALo, aHH, WssHi, WssLo, S_, H_, cs, tid, lane, wv);
                    ep_small(cs, bss, S_, 2, tix, e0, opsL, seA, seF, outS, MAXSY_ * S_, S_, lane, wv);
                }
            }
            ++epoch; gbar(bar, 16 * epoch);
        }

        __syncthreads();
        if (tid < 64) {
            int o = opsL[tid * L_ + tix];
            if (o == 1)      spA[tid]++;
            else if (o == 2) seA[tid]++;
            else           { beA[tid]++; spA[tid]--; }
            int sp = spA[tid];
            int ti = sp - 1; ti = ti < 0 ? 0 : (ti > STK_ - 1 ? STK_ - 1 : ti);
            aStk[tid] = ((e0 + tid) * STK_ + ti) * F_;
        }
        __syncthreads();
    }
}

// ======================= fallback (fp32 kernel) =======================
__device__ __forceinline__ void fdot4(const float* __restrict__ row,
                                      const float* __restrict__ x0, const float* __restrict__ x1,
                                      const float* __restrict__ x2, const float* __restrict__ x3,
                                      int K4, float& r0, float& r1, float& r2, float& r3)
{
    const float4* r  = (const float4*)row;
    const float4* p0 = (const float4*)x0; const float4* p1 = (const float4*)x1;
    const float4* p2 = (const float4*)x2; const float4* p3 = (const float4*)x3;
    float s0=0.f,s1=0.f,s2=0.f,s3=0.f,t0=0.f,t1=0.f,t2=0.f,t3=0.f;
    for (int i = 0; i < K4; i += 2) {
        float4 w0 = r[i], w1 = r[i+1]; float4 v;
        v=p0[i]; s0+=w0.x*v.x; s0+=w0.y*v.y; s0+=w0.z*v.z; s0+=w0.w*v.w;
        v=p0[i+1]; t0+=w1.x*v.x; t0+=w1.y*v.y; t0+=w1.z*v.z; t0+=w1.w*v.w;
        v=p1[i]; s1+=w0.x*v.x; s1+=w0.y*v.y; s1+=w0.z*v.z; s1+=w0.w*v.w;
        v=p1[i+1]; t1+=w1.x*v.x; t1+=w1.y*v.y; t1+=w1.z*v.z; t1+=w1.w*v.w;
        v=p2[i]; s2+=w0.x*v.x; s2+=w0.y*v.y; s2+=w0.z*v.z; s2+=w0.w*v.w;
        v=p2[i+1]; t2+=w1.x*v.x; t2+=w1.y*v.y; t2+=w1.z*v.z; t2+=w1.w*v.w;
        v=p3[i]; s3+=w0.x*v.x; s3+=w0.y*v.y; s3+=w0.z*v.z; s3+=w0.w*v.w;
        v=p3[i+1]; t3+=w1.x*v.x; t3+=w1.y*v.y; t3+=w1.z*v.z; t3+=w1.w*v.w;
    }
    r0=s0+t0; r1=s1+t1; r2=s2+t2; r3=s3+t3;
}
__device__ __forceinline__ float fdot1(const float* __restrict__ row,
                                       const float* __restrict__ x, int K4)
{
    const float4* r = (const float4*)row; const float4* p = (const float4*)x;
    float s=0.f,t=0.f;
    for (int i = 0; i < K4; i += 2) {
        float4 w0=r[i], v0=p[i], w1=r[i+1], v1=p[i+1];
        s+=w0.x*v0.x; s+=w0.y*v0.y; s+=w0.z*v0.z; s+=w0.w*v0.w;
        t+=w1.x*v1.x; t+=w1.y*v1.y; t+=w1.z*v1.z; t+=w1.w*v1.w;
    }
    return s+t;
}
#define FB_G 4
__global__ __launch_bounds__(1024) void grass_fallback(
    const float* __restrict__ inputStacks, const int* __restrict__ ops,
    const float* __restrict__ Wd, const float* __restrict__ bd,
    const float* __restrict__ Wl, const float* __restrict__ bl,
    const float* __restrict__ Wr, const float* __restrict__ br,
    const float* __restrict__ Wsd, const float* __restrict__ bsd,
    const float* __restrict__ Wsf, const float* __restrict__ bsf,
    const float* __restrict__ Wss, const float* __restrict__ bss,
    const float* __restrict__ Wbox, const float* __restrict__ bbox,
    float* __restrict__ out)
{
    __shared__ float stk[FB_G][STK_][F_];
    __shared__ float hh[FB_G][H_];
    __shared__ float boxtmp[FB_G][MAXB_][BOX_];
    __shared__ float symtmp[FB_G][MAXSY_][S_];
    const int t = threadIdx.x, b0 = blockIdx.x * FB_G;
    for (int idx = t; idx < FB_G*F_; idx += 1024) {
        int g = idx >> 9, k = idx & (F_-1);
        stk[g][0][k] = inputStacks[(size_t)(b0+g)*F_ + k];
    }
    for (int idx = t; idx < FB_G*H_; idx += 1024) hh[idx>>10][idx&(H_-1)] = 0.f;
    int sp[FB_G], bc[FB_G], sc[FB_G];
#pragma unroll
    for (int g = 0; g < FB_G; ++g) { sp[g]=1; bc[g]=0; sc[g]=0; }
    __syncthreads();
    for (int step = 0; step < L_; ++step) {
        int op[FB_G], ti[FB_G], ri[FB_G]; bool a1=false,a2=false,a0=false;
#pragma unroll
        for (int g = 0; g < FB_G; ++g) {
            op[g] = ops[(size_t)(b0+g)*L_ + (L_-1-step)];
            int tt = sp[g]-1; tt = tt<0?0:(tt>STK_-1?STK_-1:tt); ti[g]=tt;
            int rr = sp[g]; ri[g] = rr>STK_-1?STK_-1:rr;
            a1 |= (op[g]==1); a2 |= (op[g]==2); a0 |= (op[g]==0);
        }
        const float *x0=stk[0][ti[0]], *x1=stk[1][ti[1]], *x2=stk[2][ti[2]], *x3=stk[3][ti[3]];
        if (a1) {
            float r0,r1,r2,r3; fdot4(Wd+(size_t)t*F_, x0,x1,x2,x3, F_/4, r0,r1,r2,r3);
            float bb = bd[t];
            if (op[0]==1) hh[0][t]=tanhf(r0+bb); if (op[1]==1) hh[1][t]=tanhf(r1+bb);
            if (op[2]==1) hh[2][t]=tanhf(r2+bb); if (op[3]==1) hh[3][t]=tanhf(r3+bb);
        }
        if (a2) {
            float r0,r1,r2,r3; fdot4(Wsd+(size_t)t*F_, x0,x1,x2,x3, F_/4, r0,r1,r2,r3);
            float bb = bsd[t];
            if (op[0]==2) hh[0][t]=tanhf(r0+bb); if (op[1]==2) hh[1][t]=tanhf(r1+bb);
            if (op[2]==2) hh[2][t]=tanhf(r2+bb); if (op[3]==2) hh[3][t]=tanhf(r3+bb);
        }
        if (a0 && t < FB_G*BOX_) {
            int g = t / BOX_, cc = t - g*BOX_;
            if (op[g]==0) {
                float acc = fdot1(Wbox+(size_t)cc*F_, stk[g][ti[g]], F_/4);
                boxtmp[g][bc[g]][cc] = tanhf(acc + bbox[cc]);
            }
        }
        __syncthreads();
        if (a1) {
            if (t < F_) {
                float r0,r1,r2,r3; fdot4(Wl+(size_t)t*H_, hh[0],hh[1],hh[2],hh[3], H_/4, r0,r1,r2,r3);
                float bb = bl[t];
                if (op[0]==1) stk[0][ti[0]][t]=tanhf(r0+bb); if (op[1]==1) stk[1][ti[1]][t]=tanhf(r1+bb);
                if (op[2]==1) stk[2][ti[2]][t]=tanhf(r2+bb); if (op[3]==1) stk[3][ti[3]][t]=tanhf(r3+bb);
            } else {
                int m = t - F_;
                float r0,r1,r2,r3; fdot4(Wr+(size_t)m*H_, hh[0],hh[1],hh[2],hh[3], H_/4, r0,r1,r2,r3);
                float bb = br[m];
                if (op[0]==1) stk[0][ri[0]][m]=tanhf(r0+bb); if (op[1]==1) stk[1][ri[1]][m]=tanhf(r1+bb);
                if (op[2]==1) stk[2][ri[2]][m]=tanhf(r2+bb); if (op[3]==1) stk[3][ri[3]][m]=tanhf(r3+bb);
            }
        }
        if (a2) {
            if (t < F_) {
                float r0,r1,r2,r3; fdot4(Wsf+(size_t)t*H_, hh[0],hh[1],hh[2],hh[3], H_/4, r0,r1,r2,r3);
                float bb = bsf[t];
                if (op[0]==2) stk[0][ti[0]][t]=tanhf(r0+bb); if (op[1]==2) stk[1][ti[1]][t]=tanhf(r1+bb);
                if (op[2]==2) stk[2][ti[2]][t]=tanhf(r2+bb); if (op[3]==2) stk[3][ti[3]][t]=tanhf(r3+bb);
            } else if (t < F_ + FB_G*S_) {
                int idx = t - F_, g = idx >> 3, cc = idx & 7;
                if (op[g]==2) {
                    float acc = fdot1(Wss+(size_t)cc*H_, hh[g], H_/4);
                    symtmp[g][sc[g]][cc] = tanhf(acc + bss[cc]);
                }
            }
        }
        __syncthreads();
#pragma unroll
        for (int g = 0; g < FB_G; ++g) {
            if (op[g]==1) sp[g]++;
            else if (op[g]==2) sc[g]++;
            else { bc[g]++; sp[g]--; }
        }
    }
#pragma unroll
    for (int g = 0; g < FB_G; ++g) {
        int b = b0 + g;
        float* ob = out + (size_t)b * MAXB_ * BOX_;
        for (int idx = t; idx < MAXB_*BOX_; idx += 1024) {
            int jj = idx / BOX_, cc = idx - jj*BOX_;
            int e = bc[g] - 1 - jj;
            ob[idx] = (e >= 0) ? boxtmp[g][e][cc] : 0.f;
        }
        float* os = out + (size_t)B_*MAXB_*BOX_ + (size_t)b * MAXSY_ * S_;
        for (int idx = t; idx < MAXSY_*S_; idx += 1024) {
            int jj = idx >> 3, cc = idx & 7;
            int e = sc[g] - 1 - jj;
            os[idx] = (e >= 0) ? symtmp[g][e][cc] : 0.f;
        }
    }
}

// ---------------- launcher ----------------
extern "C" void kernel_launch(void* const* d_in, const int* in_sizes, int n_in,
                              void* d_out, int out_size, void* d_ws, size_t ws_size,
                              hipStream_t stream) {
    (void)in_sizes; (void)n_in;
    const float* X    = (const float*)d_in[0];
    const int*   ops  = (const int*)d_in[1];
    const float* Wd   = (const float*)d_in[2];  const float* bd   = (const float*)d_in[3];
    const float* Wl   = (const float*)d_in[4];  const float* bl   = (const float*)d_in[5];
    const float* Wr   = (const float*)d_in[6];  const float* br   = (const float*)d_in[7];
    const float* Wsd  = (const float*)d_in[8];  const float* bsd  = (const float*)d_in[9];
    const float* Wsf  = (const float*)d_in[10]; const float* bsf  = (const float*)d_in[11];
    const float* Wss  = (const float*)d_in[12]; const float* bss  = (const float*)d_in[13];
    const float* Wbox = (const float*)d_in[14]; const float* bbox = (const float*)d_in[15];
    float* out = (float*)d_out;

    if (ws_size < WS_NEED) {
        grass_fallback<<<dim3(B_/FB_G), dim3(1024), 0, stream>>>(
            X, ops, Wd, bd, Wl, bl, Wr, br, Wsd, bsd, Wsf, bsf, Wss, bss, Wbox, bbox, out);
        return;
    }
    char* ws = (char*)d_ws;
    hipMemsetAsync(d_out, 0, (size_t)out_size * sizeof(float), stream);  // zero-pad slots
    hipMemsetAsync(ws, 0, 4096, stream);                                 // barrier counters + flag
    grass_prep<<<dim3(512), dim3(256), 0, stream>>>(X, ops, Wd, Wl, Wr, Wsd, Wsf, Wss, Wbox, ws);
    grass_pipe<<<dim3(128), dim3(512), 0, stream>>>(bd, bl, br, bsd, bsf, bss, bbox, ws, out);
    grass_legacy<<<dim3(256), dim3(256), 0, stream>>>(ops, bd, bl, br, bsd, bsf, bss, bbox, ws, out);
}

// Round 5
// 2740.396 us; speedup vs baseline: 2.0609x; 2.0609x over previous
//
#include <hip/hip_runtime.h>
#include <stdint.h>

// ---------------- problem constants ----------------
#define B_     1024
#define F_     512
#define H_     1024
#define S_     8
#define BOX_   12
#define MAXB_  64
#define MAXSY_ 64
#define L_     126
#define STK_   3
#define NCYC_  42

typedef unsigned short u16;
typedef unsigned int   u32;
typedef unsigned long long u64;
typedef __attribute__((ext_vector_type(8))) short sh8;   // 8 bf16 (4 VGPRs)
typedef __attribute__((ext_vector_type(4))) int   i4;    // 16B payload
typedef __attribute__((ext_vector_type(4))) float f4;    // MFMA accumulator

#define MFMA16(a,b,c) __builtin_amdgcn_mfma_f32_16x16x32_bf16((a),(b),(c),0,0,0)

// HW_REG_XCC_ID (id=20), offset 0, size 32  [measured working on MI355X: learn_hip m09]
#define XCC_ID_IMM (((32 - 1) << 11) | (0 << 6) | 20)

// ---------------- ws layout (bytes) ----------------
constexpr size_t PL_HF = (size_t)H_ * F_ * 2;      // 1 MB  (Wd, Wsd planes)
constexpr size_t PL_FH = (size_t)F_ * H_ * 2;      // 1 MB  (Wl, Wr, Wsf planes)
constexpr size_t PL_SS = 16384;                    // S*H*2
constexpr size_t PL_BX = 16384;                    // BOX*F*2=12288, padded
constexpr size_t O_WdHi  = 4096;
constexpr size_t O_WdLo  = O_WdHi  + PL_HF;
constexpr size_t O_WsdHi = O_WdLo  + PL_HF;
constexpr size_t O_WsdLo = O_WsdHi + PL_HF;
constexpr size_t O_WlHi  = O_WsdLo + PL_HF;
constexpr size_t O_WlLo  = O_WlHi  + PL_FH;
constexpr size_t O_WrHi  = O_WlLo  + PL_FH;
constexpr size_t O_WrLo  = O_WrHi  + PL_FH;
constexpr size_t O_WsfHi = O_WrLo  + PL_FH;
constexpr size_t O_WsfLo = O_WsfHi + PL_FH;
constexpr size_t O_WssHi = O_WsfLo + PL_FH;
constexpr size_t O_WssLo = O_WssHi + PL_SS;
constexpr size_t O_WbxHi = O_WssLo + PL_SS;
constexpr size_t O_WbxLo = O_WbxHi + PL_BX;
constexpr size_t SZ_STK  = (size_t)B_ * STK_ * F_ * 2;   // 3 MB per plane
constexpr size_t O_SHi   = O_WbxLo + PL_BX;
constexpr size_t O_SLo   = O_SHi   + SZ_STK;
constexpr size_t SZ_H    = (size_t)B_ * H_ * 2;          // 2 MB per plane
constexpr size_t O_HAHi  = O_SLo   + SZ_STK;
constexpr size_t O_HALo  = O_HAHi  + SZ_H;
constexpr size_t O_HSHi  = O_HALo  + SZ_H;
constexpr size_t O_HSLo  = O_HSHi  + SZ_H;
constexpr size_t SZ_FB   = (size_t)B_ * 512 * 2;         // 1 MB per plane
constexpr size_t O_FB0Hi = O_HSLo  + SZ_H;
constexpr size_t O_FB0Lo = O_FB0Hi + SZ_FB;
constexpr size_t O_FB1Hi = O_FB0Lo + SZ_FB;
constexpr size_t O_FB1Lo = O_FB1Hi + SZ_FB;
constexpr size_t WS_NEED = O_FB1Lo + SZ_FB;              // ~28.2 MB
// control area (first 4096 B, memset to 0): [0,2048) barrier counters,
// 2048 nonuni flag, 2176 per-group fail flags (16 ints), 2304 per-group-per-role xcd ids.
constexpr size_t O_FLAG  = 2048;
constexpr size_t O_GFAIL = 2176;
constexpr size_t O_GXCD  = 2304;   // 16 groups * 16 roles * 4 B = 1024 B

// ---------------- numeric helpers ----------------
__device__ __forceinline__ float bf2float(u16 h) {
    union { u32 u; float f; } v; v.u = ((u32)h) << 16; return v.f;
}
__device__ __forceinline__ u16 bfhi_of(float f) {           // RNE fp32->bf16
    union { float f; u32 u; } v; v.f = f;
    u32 u = v.u;
    return (u16)((u + 0x7fffu + ((u >> 16) & 1u)) >> 16);
}
__device__ __forceinline__ void split2(float x, u16& hi, u16& lo) {
    hi = bfhi_of(x);
    lo = bfhi_of(x - bf2float(hi));
}

// ---------------- store helpers ----------------
// DC=true : device-coherent (sc0 sc1) -> LLC, cross-XCD safe (legacy path)
// DC=false: plain store -> lands in this XCD's L2 (write-through L1); group-local
template<bool DC>
__device__ __forceinline__ void cst(u16* p, u16 v) {
    if (DC) asm volatile("global_store_short %0, %1, off sc0 sc1"
                         :: "v"(p), "v"((u32)v) : "memory");
    else    asm volatile("global_store_short %0, %1, off"
                         :: "v"(p), "v"((u32)v) : "memory");
}
__device__ __forceinline__ void vdrain() {
    asm volatile("s_waitcnt vmcnt(0)" ::: "memory");
}

// sc0-only batched 16B loads: bypass stale L1, read from (XCD-shared) L2. MLP=8.
__device__ __forceinline__ void cld8(i4& d0, i4& d1, i4& d2, i4& d3,
                                     i4& d4, i4& d5, i4& d6, i4& d7,
    const u16* p0, const u16* p1, const u16* p2, const u16* p3,
    const u16* p4, const u16* p5, const u16* p6, const u16* p7)
{
    asm volatile(
        "global_load_dwordx4 %0, %8, off sc0\n\t"
        "global_load_dwordx4 %1, %9, off sc0\n\t"
        "global_load_dwordx4 %2, %10, off sc0\n\t"
        "global_load_dwordx4 %3, %11, off sc0\n\t"
        "global_load_dwordx4 %4, %12, off sc0\n\t"
        "global_load_dwordx4 %5, %13, off sc0\n\t"
        "global_load_dwordx4 %6, %14, off sc0\n\t"
        "global_load_dwordx4 %7, %15, off sc0\n\t"
        "s_waitcnt vmcnt(0)"
        : "=&v"(d0),"=&v"(d1),"=&v"(d2),"=&v"(d3),
          "=&v"(d4),"=&v"(d5),"=&v"(d6),"=&v"(d7)
        : "v"(p0),"v"(p1),"v"(p2),"v"(p3),"v"(p4),"v"(p5),"v"(p6),"v"(p7));
}

// ---------------- prep: split weights + input stacks; detect pattern ----------------
__device__ void split_range(const float* __restrict__ s, u16* hi, u16* lo,
                            int n, int t0, int stride) {
    for (int i = t0; i < n; i += stride) {
        float v = s[i];
        u16 h = bfhi_of(v);
        hi[i] = h;
        lo[i] = bfhi_of(v - bf2float(h));
    }
}

__global__ void grass_prep(const float* __restrict__ X, const int* __restrict__ ops,
                           const float* __restrict__ Wd, const float* __restrict__ Wl,
                           const float* __restrict__ Wr, const float* __restrict__ Wsd,
                           const float* __restrict__ Wsf, const float* __restrict__ Wss,
                           const float* __restrict__ Wbox, char* __restrict__ ws)
{
    const int t0 = blockIdx.x * blockDim.x + threadIdx.x;
    const int st = gridDim.x * blockDim.x;
    split_range(Wd,  (u16*)(ws + O_WdHi),  (u16*)(ws + O_WdLo),  H_ * F_, t0, st);
    split_range(Wsd, (u16*)(ws + O_WsdHi), (u16*)(ws + O_WsdLo), H_ * F_, t0, st);
    split_range(Wl,  (u16*)(ws + O_WlHi),  (u16*)(ws + O_WlLo),  F_ * H_, t0, st);
    split_range(Wr,  (u16*)(ws + O_WrHi),  (u16*)(ws + O_WrLo),  F_ * H_, t0, st);
    split_range(Wsf, (u16*)(ws + O_WsfHi), (u16*)(ws + O_WsfLo), F_ * H_, t0, st);
    split_range(Wss, (u16*)(ws + O_WssHi), (u16*)(ws + O_WssLo), S_ * H_, t0, st);
    split_range(Wbox,(u16*)(ws + O_WbxHi), (u16*)(ws + O_WbxLo), BOX_ * F_, t0, st);
    u16* SHi = (u16*)(ws + O_SHi);
    u16* SLo = (u16*)(ws + O_SLo);
    for (int i = t0; i < B_ * F_; i += st) {
        int e = i >> 9, k = i & (F_ - 1);
        float v = X[i];
        u16 h = bfhi_of(v);
        size_t off = (size_t)e * STK_ * F_ + k;     // slot 0
        SHi[off] = h;
        SLo[off] = bfhi_of(v - bf2float(h));
    }
    // pattern check: stored order expects {0,2,1}[t%3]
    int* flag = (int*)(ws + O_FLAG);
    for (int i = t0; i < B_ * L_; i += st) {
        int t = i % L_;
        int tm = t % 3;
        int expect = (tm == 0) ? 0 : ((tm == 1) ? 2 : 1);
        if (ops[i] != expect) {
            __hip_atomic_store(flag, 1, __ATOMIC_RELAXED, __HIP_MEMORY_SCOPE_AGENT);
            break;
        }
    }
}

// -------- group barrier (counters are device-coherent atomics at LLC; the DATA
// ordering contract is: participant drains vmcnt (stores at their coherence
// point: L2 for pipe / LLC for legacy) before signaling). --------
__device__ __forceinline__ void gbar(int* bar, int target) {
    vdrain();
    __syncthreads();
    if (threadIdx.x == 0) {
        __hip_atomic_fetch_add(bar, 1, __ATOMIC_RELAXED, __HIP_MEMORY_SCOPE_AGENT);
        while (__hip_atomic_load(bar, __ATOMIC_RELAXED, __HIP_MEMORY_SCOPE_AGENT) < target)
            __builtin_amdgcn_s_sleep(2);
    }
    __syncthreads();
}
__device__ __forceinline__ void gwait(int* ctr, int target) {
    if (threadIdx.x == 0) {
        while (__hip_atomic_load(ctr, __ATOMIC_RELAXED, __HIP_MEMORY_SCOPE_AGENT) < target)
            __builtin_amdgcn_s_sleep(2);
    }
    __syncthreads();
}

// ---------------- activation staging, pipe (sc0/L2): 256 threads ----------------
__device__ __forceinline__ void stageA_c(u16* __restrict__ lds,
    const u16* __restrict__ AHi, const u16* __restrict__ ALo,
    const int* __restrict__ aOff, int kbase, int tid)
{
    const int wv = tid >> 6, lane = tid & 63;
    const int kk = kbase + lane * 8;
    int off[16];
#pragma unroll
    for (int i = 0; i < 16; ++i) off[i] = aOff[i * 4 + wv] + kk;
    const int lx = lane * 8;
#pragma unroll
    for (int half = 0; half < 2; ++half) {
        const u16* A = half ? ALo : AHi;
        u16* L = lds + (half ? 32768 : 0);
#pragma unroll
        for (int b = 0; b < 2; ++b) {
            const int i0 = b * 8;
            i4 d0,d1,d2,d3,d4,d5,d6,d7;
            cld8(d0,d1,d2,d3,d4,d5,d6,d7,
                 A+off[i0+0], A+off[i0+1], A+off[i0+2], A+off[i0+3],
                 A+off[i0+4], A+off[i0+5], A+off[i0+6], A+off[i0+7]);
#define STO(ii, dv) { const int m = (i0 + ii) * 4 + wv; \
                      *(i4*)(L + m * 512 + (lx ^ ((m & 7) << 3))) = dv; }
            STO(0,d0) STO(1,d1) STO(2,d2) STO(3,d3)
            STO(4,d4) STO(5,d5) STO(6,d6) STO(7,d7)
#undef STO
        }
    }
}

// ---------------- activation staging, legacy (sc0sc1/LLC): 256 threads ----------------
__device__ __forceinline__ void stageA_dc(u16* __restrict__ lds,
    const u16* __restrict__ AHi, const u16* __restrict__ ALo,
    const int* __restrict__ aOff, int kbase, int tid)
{
    const int wv = tid >> 6, lane = tid & 63;
    const int kk = kbase + lane * 8;
    int off[16];
#pragma unroll
    for (int i = 0; i < 16; ++i) off[i] = aOff[i * 4 + wv] + kk;
    u64 v[64];
#pragma unroll
    for (int i = 0; i < 16; ++i) {
        const u64* s = (const u64*)(AHi + off[i]);
        v[2 * i]     = __hip_atomic_load(s,     __ATOMIC_RELAXED, __HIP_MEMORY_SCOPE_AGENT);
        v[2 * i + 1] = __hip_atomic_load(s + 1, __ATOMIC_RELAXED, __HIP_MEMORY_SCOPE_AGENT);
    }
#pragma unroll
    for (int i = 0; i < 16; ++i) {
        const u64* s = (const u64*)(ALo + off[i]);
        v[32 + 2 * i] = __hip_atomic_load(s,     __ATOMIC_RELAXED, __HIP_MEMORY_SCOPE_AGENT);
        v[33 + 2 * i] = __hip_atomic_load(s + 1, __ATOMIC_RELAXED, __HIP_MEMORY_SCOPE_AGENT);
    }
#pragma unroll
    for (int i = 0; i < 16; ++i) {
        const int m = i * 4 + wv;
        u16* d = lds + m * 512 + ((lane * 8) ^ ((m & 7) << 3));
        ((u64*)d)[0] = v[2 * i];
        ((u64*)d)[1] = v[2 * i + 1];
        u64* d2 = (u64*)(d + 32768);
        d2[0] = v[32 + 2 * i];
        d2[1] = v[33 + 2 * i];
    }
}

// ---------------- 64x64 split-bf16 k-loop over one staged 512-col panel ----------
__device__ __forceinline__ void kloop64(const u16* __restrict__ lds,
    const u16* __restrict__ WHi, const u16* __restrict__ WLo,
    int nRow0, int Kw, int kofs, f4 c[2][2], int lane, int wv4)
{
    const int quad = lane >> 4, mr = lane & 15;
    const int mh = wv4 & 1, nh = (wv4 >> 1) & 1;
    const int m0 = (mh * 2) * 16 + mr, m1 = m0 + 16;
    const int n0 = nRow0 + (nh * 2) * 16 + mr, n1 = n0 + 16;
    const u16* b0h = WHi + (size_t)n0 * Kw + kofs;
    const u16* b1h = WHi + (size_t)n1 * Kw + kofs;
    const u16* b0l = WLo + (size_t)n0 * Kw + kofs;
    const u16* b1l = WLo + (size_t)n1 * Kw + kofs;
    const int sw = (m0 & 7) << 3;
    const u16* A0h = lds + m0 * 512;
    const u16* A1h = lds + m1 * 512;
#pragma unroll 2
    for (int kb = 0; kb < 512; kb += 64) {
        const int k0 = kb + quad * 8, k1 = k0 + 32;
        const int x0 = k0 ^ sw, x1 = k1 ^ sw;
        sh8 B0H0 = *(const sh8*)(b0h + k0), B1H0 = *(const sh8*)(b1h + k0);
        sh8 B0L0 = *(const sh8*)(b0l + k0), B1L0 = *(const sh8*)(b1l + k0);
        sh8 B0H1 = *(const sh8*)(b0h + k1), B1H1 = *(const sh8*)(b1h + k1);
        sh8 B0L1 = *(const sh8*)(b0l + k1), B1L1 = *(const sh8*)(b1l + k1);
        sh8 A0H0 = *(const sh8*)(A0h + x0);
        sh8 A1H0 = *(const sh8*)(A1h + x0);
        sh8 A0L0 = *(const sh8*)(A0h + 32768 + x0);
        sh8 A1L0 = *(const sh8*)(A1h + 32768 + x0);
        sh8 A0H1 = *(const sh8*)(A0h + x1);
        sh8 A1H1 = *(const sh8*)(A1h + x1);
        sh8 A0L1 = *(const sh8*)(A0h + 32768 + x1);
        sh8 A1L1 = *(const sh8*)(A1h + 32768 + x1);
        c[0][0]=MFMA16(A0H0,B0H0,c[0][0]); c[0][1]=MFMA16(A0H0,B1H0,c[0][1]);
        c[1][0]=MFMA16(A1H0,B0H0,c[1][0]); c[1][1]=MFMA16(A1H0,B1H0,c[1][1]);
        c[0][0]=MFMA16(A0H0,B0L0,c[0][0]); c[0][1]=MFMA16(A0H0,B1L0,c[0][1]);
        c[1][0]=MFMA16(A1H0,B0L0,c[1][0]); c[1][1]=MFMA16(A1H0,B1L0,c[1][1]);
        c[0][0]=MFMA16(A0L0,B0H0,c[0][0]); c[0][1]=MFMA16(A0L0,B1H0,c[0][1]);
        c[1][0]=MFMA16(A1L0,B0H0,c[1][0]); c[1][1]=MFMA16(A1L0,B1H0,c[1][1]);
        c[0][0]=MFMA16(A0H1,B0H1,c[0][0]); c[0][1]=MFMA16(A0H1,B1H1,c[0][1]);
        c[1][0]=MFMA16(A1H1,B0H1,c[1][0]); c[1][1]=MFMA16(A1H1,B1H1,c[1][1]);
        c[0][0]=MFMA16(A0H1,B0L1,c[0][0]); c[0][1]=MFMA16(A0H1,B1L1,c[0][1]);
        c[1][0]=MFMA16(A1H1,B0L1,c[1][0]); c[1][1]=MFMA16(A1H1,B1L1,c[1][1]);
        c[0][0]=MFMA16(A0L1,B0H1,c[0][0]); c[0][1]=MFMA16(A0L1,B1H1,c[0][1]);
        c[1][0]=MFMA16(A1L1,B0H1,c[1][0]); c[1][1]=MFMA16(A1L1,B1H1,c[1][1]);
    }
}

// 64 x (<=16): wave wv (0..3) owns rows wv*16..+16.
__device__ __forceinline__ void kloop16(const u16* __restrict__ lds,
    const u16* __restrict__ WHi, const u16* __restrict__ WLo,
    int nValid, int Kw, int kofs, f4& c, int lane, int wv)
{
    const int quad = lane >> 4, mr = lane & 15;
    const int m = wv * 16 + mr;
    const int sm = (m & 7) << 3;
    const u16* Am = lds + m * 512;
    const bool nb = (mr < nValid);
    const u16* bh = WHi + (size_t)mr * Kw + kofs;
    const u16* bl = WLo + (size_t)mr * Kw + kofs;
#pragma unroll 2
    for (int kb = 0; kb < 512; kb += 64) {
        const int k0 = kb + quad * 8, k1 = k0 + 32;
        const int x0 = k0 ^ sm, x1 = k1 ^ sm;
        sh8 bH0 = {0,0,0,0,0,0,0,0}, bL0 = {0,0,0,0,0,0,0,0};
        sh8 bH1 = {0,0,0,0,0,0,0,0}, bL1 = {0,0,0,0,0,0,0,0};
        if (nb) {
            bH0 = *(const sh8*)(bh + k0); bL0 = *(const sh8*)(bl + k0);
            bH1 = *(const sh8*)(bh + k1); bL1 = *(const sh8*)(bl + k1);
        }
        sh8 aH0 = *(const sh8*)(Am + x0);
        sh8 aL0 = *(const sh8*)(Am + 32768 + x0);
        sh8 aH1 = *(const sh8*)(Am + x1);
        sh8 aL1 = *(const sh8*)(Am + 32768 + x1);
        c = MFMA16(aH0, bH0, c);
        c = MFMA16(aH0, bL0, c);
        c = MFMA16(aL0, bH0, c);
        c = MFMA16(aH1, bH1, c);
        c = MFMA16(aH1, bL1, c);
        c = MFMA16(aL1, bH1, c);
    }
}

__device__ __forceinline__ void zacc(f4 c[2][2]) {
    f4 z = {0.f, 0.f, 0.f, 0.f};
    c[0][0] = z; c[0][1] = z; c[1][0] = z; c[1][1] = z;
}

// legacy: stage(sc1) + k-loop
__device__ __forceinline__ void gemmK(u16* __restrict__ Ab,
    const u16* __restrict__ AHi, const u16* __restrict__ ALo, const int* __restrict__ aOff,
    const u16* __restrict__ WHi, const u16* __restrict__ WLo, int nRow0, int Kw,
    f4 c[2][2], int tid, int lane, int wv)
{
    zacc(c);
    for (int h = 0; h < Kw; h += 512) {
        __syncthreads();
        stageA_dc(Ab, AHi, ALo, aOff, h, tid);
        __syncthreads();
        kloop64(Ab, WHi, WLo, nRow0, Kw, h, c, lane, wv);
    }
}
__device__ __forceinline__ void gemmK16(u16* __restrict__ Ab,
    const u16* __restrict__ AHi, const u16* __restrict__ ALo, const int* __restrict__ aOff,
    const u16* __restrict__ WHi, const u16* __restrict__ WLo, int nValid, int Kw,
    f4& c, int tid, int lane, int wv)
{
    f4 z = {0.f, 0.f, 0.f, 0.f};
    c = z;
    for (int h = 0; h < Kw; h += 512) {
        __syncthreads();
        stageA_dc(Ab, AHi, ALo, aOff, h, tid);
        __syncthreads();
        kloop16(Ab, WHi, WLo, nValid, Kw, h, c, tid & 63, tid >> 6);
    }
}

// pipe: 128-col tile = two 64-col sub-tiles accumulated over staged halves (sc0 stage)
__device__ __forceinline__ void pipe_gemm128(u16* __restrict__ Ab,
    const u16* __restrict__ AHi, const u16* __restrict__ ALo, const int* __restrict__ aOff,
    const u16* __restrict__ WHi, const u16* __restrict__ WLo, int col0, int Kw,
    f4 cA[2][2], f4 cB[2][2], int tid, int lane, int wv)
{
    zacc(cA); zacc(cB);
    for (int h = 0; h < Kw; h += 512) {
        __syncthreads();
        stageA_c(Ab, AHi, ALo, aOff, h, tid);
        __syncthreads();
        kloop64(Ab, WHi, WLo, col0,      Kw, h, cA, lane, wv);
        kloop64(Ab, WHi, WLo, col0 + 64, Kw, h, cB, lane, wv);
    }
}

// ---------------- epilogues (C/D map: col=lane&15, row=(lane>>4)*4+reg) ----------
template<bool DC>
__device__ __forceinline__ void ep_h(const f4 c[2][2], const float* __restrict__ bias,
                                     int colBase, int e0, u16* DHi, u16* DLo,
                                     int lane, int wv4)
{
    const int quad = lane >> 4, mr = lane & 15;
    const int mh = wv4 & 1, nh = (wv4 >> 1) & 1;
#pragma unroll
    for (int mi = 0; mi < 2; ++mi)
#pragma unroll
    for (int ni = 0; ni < 2; ++ni)
#pragma unroll
    for (int r = 0; r < 4; ++r) {
        int mm = (mh * 2 + mi) * 16 + quad * 4 + r;
        int nn = (nh * 2 + ni) * 16 + mr;
        float v = tanhf(c[mi][ni][r] + bias[colBase + nn]);
        u16 hi, lo; split2(v, hi, lo);
        size_t off = (size_t)(e0 + mm) * H_ + colBase + nn;
        cst<DC>(DHi + off, hi);
        cst<DC>(DLo + off, lo);
    }
}

template<bool DC>
__device__ __forceinline__ void ep_slot(const f4 c[2][2], const float* __restrict__ bias,
                                        int colBase, int slot, int e0,
                                        u16* SHi, u16* SLo, int lane, int wv4)
{
    const int quad = lane >> 4, mr = lane & 15;
    const int mh = wv4 & 1, nh = (wv4 >> 1) & 1;
#pragma unroll
    for (int mi = 0; mi < 2; ++mi)
#pragma unroll
    for (int ni = 0; ni < 2; ++ni)
#pragma unroll
    for (int r = 0; r < 4; ++r) {
        int mm = (mh * 2 + mi) * 16 + quad * 4 + r;
        int nn = (nh * 2 + ni) * 16 + mr;
        float v = tanhf(c[mi][ni][r] + bias[colBase + nn]);
        u16 hi, lo; split2(v, hi, lo);
        size_t off = ((size_t)(e0 + mm) * STK_ + slot) * F_ + colBase + nn;
        cst<DC>(SHi + off, hi);
        cst<DC>(SLo + off, lo);
    }
}

template<bool DC>
__device__ __forceinline__ void ep_fb(const f4 c[2][2], const float* __restrict__ bias,
                                      int colBase, int e0, u16* FHi, u16* FLo,
                                      int lane, int wv4)
{
    const int quad = lane >> 4, mr = lane & 15;
    const int mh = wv4 & 1, nh = (wv4 >> 1) & 1;
#pragma unroll
    for (int mi = 0; mi < 2; ++mi)
#pragma unroll
    for (int ni = 0; ni < 2; ++ni)
#pragma unroll
    for (int r = 0; r < 4; ++r) {
        int mm = (mh * 2 + mi) * 16 + quad * 4 + r;
        int nn = (nh * 2 + ni) * 16 + mr;
        float v = tanhf(c[mi][ni][r] + bias[colBase + nn]);
        u16 hi, lo; split2(v, hi, lo);
        size_t off = (size_t)(e0 + mm) * 512 + colBase + nn;
        cst<DC>(FHi + off, hi);
        cst<DC>(FLo + off, lo);
    }
}

template<bool DC>
__device__ __forceinline__ void ep_stack(const f4 c[2][2], const float* __restrict__ bias,
                                         int colBase, int opSel, bool useRi, int tix, int e0,
                                         const unsigned char* opsL, const int* spA,
                                         u16* SHi, u16* SLo, int lane, int wv)
{
    const int quad = lane >> 4, mr = lane & 15;
    const int mh = wv & 1, nh = (wv >> 1) & 1;
#pragma unroll
    for (int mi = 0; mi < 2; ++mi)
#pragma unroll
    for (int ni = 0; ni < 2; ++ni)
#pragma unroll
    for (int r = 0; r < 4; ++r) {
        int mm = (mh * 2 + mi) * 16 + quad * 4 + r;
        int nn = (nh * 2 + ni) * 16 + mr;
        if (opsL[mm * L_ + tix] != opSel) continue;
        int sp = spA[mm];
        int slot = useRi ? sp : sp - 1;
        slot = slot < 0 ? 0 : (slot > STK_ - 1 ? STK_ - 1 : slot);
        float v = tanhf(c[mi][ni][r] + bias[colBase + nn]);
        u16 hi, lo; split2(v, hi, lo);
        size_t off = ((size_t)(e0 + mm) * STK_ + slot) * F_ + colBase + nn;
        cst<DC>(SHi + off, hi);
        cst<DC>(SLo + off, lo);
    }
}

__device__ __forceinline__ void ep_small(const f4& c, const float* __restrict__ bias,
                                         int nValid, int opSel, int tix, int e0,
                                         const unsigned char* opsL, const int* eCnt, const int* eTot,
                                         float* __restrict__ outBase, int rowStride, int ncols,
                                         int lane, int wv)
{
    const int nn = lane & 15;
    if (nn >= nValid) return;
#pragma unroll
    for (int r = 0; r < 4; ++r) {
        int mm = wv * 16 + (lane >> 4) * 4 + r;
        if (opsL[mm * L_ + tix] != opSel) continue;
        int slot = eTot[mm] - 1 - eCnt[mm];
        if (slot < 0 || slot >= 64) continue;
        float v = tanhf(c[r] + bias[nn]);
        outBase[(size_t)(e0 + mm) * rowStride + slot * ncols + nn] = v;
    }
}

__device__ __forceinline__ void ep_small_u(const f4& c, const float* __restrict__ bias,
                                           int nValid, int slot, int e0,
                                           float* __restrict__ outBase, int rowStride, int ncols,
                                           int lane, int wv)
{
    const int nn = lane & 15;
    if (nn >= nValid) return;
#pragma unroll
    for (int r = 0; r < 4; ++r) {
        int mm = wv * 16 + (lane >> 4) * 4 + r;
        outBase[(size_t)(e0 + mm) * rowStride + slot * ncols + nn] = tanhf(c[r] + bias[nn]);
    }
}

// ---------------- pipe kernel: 16 groups x (8 chain + 8 side) x 256 threads ----------
// blockIdx = role*16 + gid  => all 16 blocks of a group share blockIdx mod 8 = gid mod 8
// => same XCD under round-robin dispatch. Verified at runtime via HW_REG_XCC_ID; any
// mismatch marks the group failed and the device-coherent legacy kernel handles it.
// Within one XCD, exchange via L2: plain stores (write-through L1), sc0 loads.
__global__ __launch_bounds__(256, 1) void grass_pipe(
    const float* __restrict__ bd, const float* __restrict__ bl, const float* __restrict__ br,
    const float* __restrict__ bsd, const float* __restrict__ bsf, const float* __restrict__ bss,
    const float* __restrict__ bbox,
    char* __restrict__ ws, float* __restrict__ out)
{
    if (__hip_atomic_load((int*)(ws + O_FLAG), __ATOMIC_RELAXED, __HIP_MEMORY_SCOPE_AGENT))
        return;   // non-uniform program: legacy kernel handles everything

    const int tid  = threadIdx.x;
    const int lane = tid & 63, wv = tid >> 6;   // wv 0..3
    const int j    = blockIdx.x >> 4;           // role: 0..7 chain, 8..15 side
    const int gid  = blockIdx.x & 15;           // group (64 batch rows)
    const int e0   = gid * 64;

    const u16* WdHi  = (const u16*)(ws + O_WdHi);
    const u16* WdLo  = (const u16*)(ws + O_WdLo);
    const u16* WsdHi = (const u16*)(ws + O_WsdHi);
    const u16* WsdLo = (const u16*)(ws + O_WsdLo);
    const u16* WlHi  = (const u16*)(ws + O_WlHi);
    const u16* WlLo  = (const u16*)(ws + O_WlLo);
    const u16* WrHi  = (const u16*)(ws + O_WrHi);
    const u16* WrLo  = (const u16*)(ws + O_WrLo);
    const u16* WsfHi = (const u16*)(ws + O_WsfHi);
    const u16* WsfLo = (const u16*)(ws + O_WsfLo);
    const u16* WssHi = (const u16*)(ws + O_WssHi);
    const u16* WssLo = (const u16*)(ws + O_WssLo);
    const u16* WbxHi = (const u16*)(ws + O_WbxHi);
    const u16* WbxLo = (const u16*)(ws + O_WbxLo);
    u16* SHi  = (u16*)(ws + O_SHi);
    u16* SLo  = (u16*)(ws + O_SLo);
    u16* HAHi = (u16*)(ws + O_HAHi);
    u16* HALo = (u16*)(ws + O_HALo);
    u16* HSHi = (u16*)(ws + O_HSHi);
    u16* HSLo = (u16*)(ws + O_HSLo);
    u16* FB0Hi = (u16*)(ws + O_FB0Hi);
    u16* FB0Lo = (u16*)(ws + O_FB0Lo);
    u16* FB1Hi = (u16*)(ws + O_FB1Hi);
    u16* FB1Lo = (u16*)(ws + O_FB1Lo);
    int* cbar = (int*)ws + gid * 32;        // chain barrier (8 blocks)
    int* sbar = cbar + 1;                   // side barrier (8 blocks)
    int* pbar = cbar + 3;                   // prologue barrier (16 blocks)
    int* gx   = (int*)(ws + O_GXCD) + gid * 16;
    int* gf   = (int*)(ws + O_GFAIL) + gid;

    float* outB = out;
    float* outS = out + (size_t)B_ * MAXB_ * BOX_;

    __shared__ __align__(16) u16 Abuf[2 * 64 * 512];     // 128 KB staged A panel
    __shared__ int aS0[64], aR1[64], aR2[64], aHH[64], aFB[64];

    if (tid < 64) {
        aS0[tid] = ((e0 + tid) * STK_ + 0) * F_;
        aR1[tid] = ((e0 + tid) * STK_ + 1) * F_;
        aR2[tid] = ((e0 + tid) * STK_ + 2) * F_;
        aHH[tid] = (e0 + tid) * H_;
        aFB[tid] = (e0 + tid) * 512;
    }

    // ---- XCD homogeneity check (correctness gate for L2 exchange) ----
    const int myxcd = (int)(__builtin_amdgcn_s_getreg(XCC_ID_IMM) & 0xf);
    if (tid == 0)
        __hip_atomic_store(gx + j, myxcd, __ATOMIC_RELAXED, __HIP_MEMORY_SCOPE_AGENT);
    gbar(pbar, 16);
    if (tid < 16) {
        int ox = __hip_atomic_load(gx + tid, __ATOMIC_RELAXED, __HIP_MEMORY_SCOPE_AGENT);
        if (ox != myxcd)
            __hip_atomic_store(gf, 1, __ATOMIC_RELAXED, __HIP_MEMORY_SCOPE_AGENT);
    }
    gbar(pbar, 32);
    if (__hip_atomic_load(gf, __ATOMIC_RELAXED, __HIP_MEMORY_SCOPE_AGENT))
        return;   // group not on one XCD -> legacy kernel will process it

    f4 cA[2][2], cB[2][2];
    f4 cs;

    if (j < 8) {
        // ===== chain: op1 only =====
        for (int cyc = 0; cyc < NCYC_; ++cyc) {
            // p1: HA = tanh(Wd @ slot0 + bd), cols j*128
            pipe_gemm128(Abuf, SHi, SLo, aS0, WdHi, WdLo, j * 128, F_, cA, cB, tid, lane, wv);
            ep_h<false>(cA, bd, j * 128,      e0, HAHi, HALo, lane, wv);
            ep_h<false>(cB, bd, j * 128 + 64, e0, HAHi, HALo, lane, wv);
            gbar(cbar, 8 * (2 * cyc + 1));
            // p2: l -> slot0 (j<4), r -> rotating slot (j>=4)
            if (j < 4) {
                pipe_gemm128(Abuf, HAHi, HALo, aHH, WlHi, WlLo, j * 128, H_, cA, cB, tid, lane, wv);
                ep_slot<false>(cA, bl, j * 128,      0, e0, SHi, SLo, lane, wv);
                ep_slot<false>(cB, bl, j * 128 + 64, 0, e0, SHi, SLo, lane, wv);
            } else {
                const int rs = 1 + (cyc & 1);
                pipe_gemm128(Abuf, HAHi, HALo, aHH, WrHi, WrLo, (j - 4) * 128, H_, cA, cB, tid, lane, wv);
                if (cyc >= 2) gwait(sbar, 8 * (2 * (cyc - 2) + 1));  // r-slot WAR vs side(cyc-2)
                ep_slot<false>(cA, br, (j - 4) * 128,      rs, e0, SHi, SLo, lane, wv);
                ep_slot<false>(cB, br, (j - 4) * 128 + 64, rs, e0, SHi, SLo, lane, wv);
            }
            gbar(cbar, 8 * (2 * cyc + 2));
        }
    } else {
        // ===== side: op2 + op0, lagging the chain by one phase =====
        const int role = j - 8;
        for (int cyc = 0; cyc < NCYC_; ++cyc) {
            gwait(cbar, 8 * (2 * cyc + 2));            // r(cyc) ready
            const int* aR = (cyc & 1) ? aR2 : aR1;
            // p1: HS = tanh(Wsd @ r + bsd)
            pipe_gemm128(Abuf, SHi, SLo, aR, WsdHi, WsdLo, role * 128, F_, cA, cB, tid, lane, wv);
            ep_h<false>(cA, bsd, role * 128,      e0, HSHi, HSLo, lane, wv);
            ep_h<false>(cB, bsd, role * 128 + 64, e0, HSHi, HSLo, lane, wv);
            gbar(sbar, 8 * (2 * cyc + 1));
            // p2: f (roles 0-3), sym (role 4), box(cyc-1) (role 5)
            if (role < 4) {
                u16* FH = (cyc & 1) ? FB1Hi : FB0Hi;
                u16* FL = (cyc & 1) ? FB1Lo : FB0Lo;
                pipe_gemm128(Abuf, HSHi, HSLo, aHH, WsfHi, WsfLo, role * 128, H_, cA, cB, tid, lane, wv);
                ep_fb<false>(cA, bsf, role * 128,      e0, FH, FL, lane, wv);
                ep_fb<false>(cB, bsf, role * 128 + 64, e0, FH, FL, lane, wv);
            } else if (role == 4) {
                f4 z = {0.f, 0.f, 0.f, 0.f}; cs = z;
                for (int h = 0; h < H_; h += 512) {
                    __syncthreads();
                    stageA_c(Abuf, HSHi, HSLo, aHH, h, tid);
                    __syncthreads();
                    kloop16(Abuf, WssHi, WssLo, S_, H_, h, cs, lane, wv);
                }
                ep_small_u(cs, bss, S_, NCYC_ - 1 - cyc, e0, outS, MAXSY_ * S_, S_, lane, wv);
            } else if (role == 5 && cyc >= 1) {
                const u16* FH = ((cyc - 1) & 1) ? FB1Hi : FB0Hi;
                const u16* FL = ((cyc - 1) & 1) ? FB1Lo : FB0Lo;
                __syncthreads();
                stageA_c(Abuf, FH, FL, aFB, 0, tid);
                __syncthreads();
                f4 z = {0.f, 0.f, 0.f, 0.f}; cs = z;
                kloop16(Abuf, WbxHi, WbxLo, BOX_, 512, 0, cs, lane, wv);
                ep_small_u(cs, bbox, BOX_, NCYC_ - (cyc - 1) - 1, e0, outB, MAXB_ * BOX_, BOX_, lane, wv);
            }
            gbar(sbar, 8 * (2 * cyc + 2));
        }
        if (role == 5) {   // final box(41): f(41) guarded by the last sbar
            const u16* FH = ((NCYC_ - 1) & 1) ? FB1Hi : FB0Hi;
            const u16* FL = ((NCYC_ - 1) & 1) ? FB1Lo : FB0Lo;
            __syncthreads();
            stageA_c(Abuf, FH, FL, aFB, 0, tid);
            __syncthreads();
            f4 z = {0.f, 0.f, 0.f, 0.f}; cs = z;
            kloop16(Abuf, WbxHi, WbxLo, BOX_, 512, 0, cs, lane, wv);
            ep_small_u(cs, bbox, BOX_, 0, e0, outB, MAXB_ * BOX_, BOX_, lane, wv);
        }
    }
}

// ---------------- legacy general kernel (non-uniform programs OR failed groups) ----
__global__ __launch_bounds__(256, 2) void grass_legacy(
    const int* __restrict__ ops,
    const float* __restrict__ bd, const float* __restrict__ bl, const float* __restrict__ br,
    const float* __restrict__ bsd, const float* __restrict__ bsf, const float* __restrict__ bss,
    const float* __restrict__ bbox,
    char* __restrict__ ws, float* __restrict__ out)
{
    const int tid  = threadIdx.x;
    const int lane = tid & 63, wv = tid >> 6;
    const int gid  = blockIdx.x >> 4;
    const int j    = blockIdx.x & 15;
    const int e0   = gid * 64;

    {
        int nonuni = __hip_atomic_load((int*)(ws + O_FLAG), __ATOMIC_RELAXED, __HIP_MEMORY_SCOPE_AGENT);
        int gfl = __hip_atomic_load((int*)(ws + O_GFAIL) + gid, __ATOMIC_RELAXED, __HIP_MEMORY_SCOPE_AGENT);
        if (!nonuni && !gfl) return;   // pipe kernel already did this group
    }

    const u16* WdHi  = (const u16*)(ws + O_WdHi);
    const u16* WdLo  = (const u16*)(ws + O_WdLo);
    const u16* WsdHi = (const u16*)(ws + O_WsdHi);
    const u16* WsdLo = (const u16*)(ws + O_WsdLo);
    const u16* WlHi  = (const u16*)(ws + O_WlHi);
    const u16* WlLo  = (const u16*)(ws + O_WlLo);
    const u16* WrHi  = (const u16*)(ws + O_WrHi);
    const u16* WrLo  = (const u16*)(ws + O_WrLo);
    const u16* WsfHi = (const u16*)(ws + O_WsfHi);
    const u16* WsfLo = (const u16*)(ws + O_WsfLo);
    const u16* WssHi = (const u16*)(ws + O_WssHi);
    const u16* WssLo = (const u16*)(ws + O_WssLo);
    const u16* WbxHi = (const u16*)(ws + O_WbxHi);
    const u16* WbxLo = (const u16*)(ws + O_WbxLo);
    u16* SHi  = (u16*)(ws + O_SHi);
    u16* SLo  = (u16*)(ws + O_SLo);
    u16* HAHi = (u16*)(ws + O_HAHi);
    u16* HALo = (u16*)(ws + O_HALo);
    u16* HSHi = (u16*)(ws + O_HSHi);
    u16* HSLo = (u16*)(ws + O_HSLo);
    int* bar = (int*)ws + gid * 32 + 2;   // distinct from pipe counters

    float* outB = out;
    float* outS = out + (size_t)B_ * MAXB_ * BOX_;

    __shared__ __align__(16) u16 Abuf[2 * 64 * 512];
    __shared__ unsigned char opsL[64 * L_];
    __shared__ int spA[64], beA[64], seA[64], beF[64], seF[64];
    __shared__ int aStk[64], aHH[64];
    __shared__ int sInfo[2];

    for (int idx = tid; idx < 64 * L_; idx += 256) {
        int e = idx / L_, t = idx - e * L_;
        opsL[idx] = (unsigned char)ops[(size_t)(e0 + e) * L_ + t];
    }
    __syncthreads();
    if (tid < 64) {
        spA[tid] = 1; beA[tid] = 0; seA[tid] = 0;
        int cb = 0, cs2 = 0;
        for (int t = 0; t < L_; ++t) {
            int o = opsL[tid * L_ + t];
            cb += (o == 0); cs2 += (o == 2);
        }
        beF[tid] = cb; seF[tid] = cs2;
        aHH[tid]  = (e0 + tid) * H_;
        aStk[tid] = ((e0 + tid) * STK_ + 0) * F_;
    }
    __syncthreads();

    int epoch = 0;
    f4 c[2][2];
    f4 cs;

    for (int step = 0; step < L_; ++step) {
        const int tix = L_ - 1 - step;
        if (wv == 0) {
            int o  = opsL[lane * L_ + tix];
            int sp = spA[lane];
            unsigned long long bo = __ballot(o  == opsL[0 * L_ + tix]);
            unsigned long long bs = __ballot(sp == spA[0]);
            if (lane == 0) {
                sInfo[0] = o;
                sInfo[1] = (bo == ~0ull && bs == ~0ull) ? 1 : 0;
            }
        }
        __syncthreads();
        const int opU = sInfo[0], uni = sInfo[1];

        if (uni) {
            if (opU == 1) {
                gemmK(Abuf, SHi, SLo, aStk, WdHi, WdLo, j * 64, F_, c, tid, lane, wv);
                ep_h<true>(c, bd, j * 64, e0, HAHi, HALo, lane, wv);
                ++epoch; gbar(bar, 16 * epoch);
                {
                    const u16* W2H = (j < 8) ? WlHi : WrHi;
                    const u16* W2L = (j < 8) ? WlLo : WrLo;
                    const float* b2 = (j < 8) ? bl : br;
                    gemmK(Abuf, HAHi, HALo, aHH, W2H, W2L, (j & 7) * 64, H_, c, tid, lane, wv);
                    ep_stack<true>(c, b2, (j & 7) * 64, 1, j >= 8, tix, e0, opsL, spA, SHi, SLo, lane, wv);
                }
                ++epoch; gbar(bar, 16 * epoch);
            } else if (opU == 2) {
                gemmK(Abuf, SHi, SLo, aStk, WsdHi, WsdLo, j * 64, F_, c, tid, lane, wv);
                ep_h<true>(c, bsd, j * 64, e0, HAHi, HALo, lane, wv);
                ++epoch; gbar(bar, 16 * epoch);
                if (j < 8) {
                    gemmK(Abuf, HAHi, HALo, aHH, WsfHi, WsfLo, j * 64, H_, c, tid, lane, wv);
                    ep_stack<true>(c, bsf, j * 64, 2, false, tix, e0, opsL, spA, SHi, SLo, lane, wv);
                } else if (j == 8) {
                    gemmK16(Abuf, HAHi, HALo, aHH, WssHi, WssLo, S_, H_, cs, tid, lane, wv);
                    ep_small(cs, bss, S_, 2, tix, e0, opsL, seA, seF, outS, MAXSY_ * S_, S_, lane, wv);
                }
                ++epoch; gbar(bar, 16 * epoch);
            } else {
                if (j == 0) {
                    gemmK16(Abuf, SHi, SLo, aStk, WbxHi, WbxLo, BOX_, F_, cs, tid, lane, wv);
                    ep_small(cs, bbox, BOX_, 0, tix, e0, opsL, beA, beF, outB, MAXB_ * BOX_, BOX_, lane, wv);
                }
            }
        } else {
            gemmK(Abuf, SHi, SLo, aStk, WdHi, WdLo, j * 64, F_, c, tid, lane, wv);
            ep_h<true>(c, bd, j * 64, e0, HAHi, HALo, lane, wv);
            gemmK(Abuf, SHi, SLo, aStk, WsdHi, WsdLo, j * 64, F_, c, tid, lane, wv);
            ep_h<true>(c, bsd, j * 64, e0, HSHi, HSLo, lane, wv);
            if (j == 0) {
                gemmK16(Abuf, SHi, SLo, aStk, WbxHi, WbxLo, BOX_, F_, cs, tid, lane, wv);
                ep_small(cs, bbox, BOX_, 0, tix, e0, opsL, beA, beF, outB, MAXB_ * BOX_, BOX_, lane, wv);
            }
            ++epoch; gbar(bar, 16 * epoch);
            if (j < 8) {
                gemmK(Abuf, HAHi, HALo, aHH, WlHi, WlLo, j * 64, H_, c, tid, lane, wv);
                ep_stack<true>(c, bl, j * 64, 1, false, tix, e0, opsL, spA, SHi, SLo, lane, wv);
                gemmK(Abuf, HSHi, HSLo, aHH, WsfHi, WsfLo, j * 64, H_, c, tid, lane, wv);
                ep_stack<true>(c, bsf, j * 64, 2, false, tix, e0, opsL, spA, SHi, SLo, lane, wv);
            } else {
                gemmK(Abuf, HAHi, HALo, aHH, WrHi, WrLo, (j - 8) * 64, H_, c, tid, lane, wv);
                ep_stack<true>(c, br, (j & 7) * 64, 1, true, tix, e0, opsL, spA, SHi, SLo, lane, wv);
                if (j == 8) {
                    gemmK16(Abuf, HSHi, HSLo, aHH, WssHi, WssLo, S_, H_, cs, tid, lane, wv);
                    ep_small(cs, bss, S_, 2, tix, e0, opsL, seA, seF, outS, MAXSY_ * S_, S_, lane, wv);
                }
            }
            ++epoch; gbar(bar, 16 * epoch);
        }

        __syncthreads();
        if (tid < 64) {
            int o = opsL[tid * L_ + tix];
            if (o == 1)      spA[tid]++;
            else if (o == 2) seA[tid]++;
            else           { beA[tid]++; spA[tid]--; }
            int sp = spA[tid];
            int ti = sp - 1; ti = ti < 0 ? 0 : (ti > STK_ - 1 ? STK_ - 1 : ti);
            aStk[tid] = ((e0 + tid) * STK_ + ti) * F_;
        }
        __syncthreads();
    }
}

// ======================= fallback (fp32 kernel) =======================
__device__ __forceinline__ void fdot4(const float* __restrict__ row,
                                      const float* __restrict__ x0, const float* __restrict__ x1,
                                      const float* __restrict__ x2, const float* __restrict__ x3,
                                      int K4, float& r0, float& r1, float& r2, float& r3)
{
    const float4* r  = (const float4*)row;
    const float4* p0 = (const float4*)x0; const float4* p1 = (const float4*)x1;
    const float4* p2 = (const float4*)x2; const float4* p3 = (const float4*)x3;
    float s0=0.f,s1=0.f,s2=0.f,s3=0.f,t0=0.f,t1=0.f,t2=0.f,t3=0.f;
    for (int i = 0; i < K4; i += 2) {
        float4 w0 = r[i], w1 = r[i+1]; float4 v;
        v=p0[i]; s0+=w0.x*v.x; s0+=w0.y*v.y; s0+=w0.z*v.z; s0+=w0.w*v.w;
        v=p0[i+1]; t0+=w1.x*v.x; t0+=w1.y*v.y; t0+=w1.z*v.z; t0+=w1.w*v.w;
        v=p1[i]; s1+=w0.x*v.x; s1+=w0.y*v.y; s1+=w0.z*v.z; s1+=w0.w*v.w;
        v=p1[i+1]; t1+=w1.x*v.x; t1+=w1.y*v.y; t1+=w1.z*v.z; t1+=w1.w*v.w;
        v=p2[i]; s2+=w0.x*v.x; s2+=w0.y*v.y; s2+=w0.z*v.z; s2+=w0.w*v.w;
        v=p2[i+1]; t2+=w1.x*v.x; t2+=w1.y*v.y; t2+=w1.z*v.z; t2+=w1.w*v.w;
        v=p3[i]; s3+=w0.x*v.x; s3+=w0.y*v.y; s3+=w0.z*v.z; s3+=w0.w*v.w;
        v=p3[i+1]; t3+=w1.x*v.x; t3+=w1.y*v.y; t3+=w1.z*v.z; t3+=w1.w*v.w;
    }
    r0=s0+t0; r1=s1+t1; r2=s2+t2; r3=s3+t3;
}
__device__ __forceinline__ float fdot1(const float* __restrict__ row,
                                       const float* __restrict__ x, int K4)
{
    const float4* r = (const float4*)row; const float4* p = (const float4*)x;
    float s=0.f,t=0.f;
    for (int i = 0; i < K4; i += 2) {
        float4 w0=r[i], v0=p[i], w1=r[i+1], v1=p[i+1];
        s+=w0.x*v0.x; s+=w0.y*v0.y; s+=w0.z*v0.z; s+=w0.w*v0.w;
        t+=w1.x*v1.x; t+=w1.y*v1.y; t+=w1.z*v1.z; t+=w1.w*v1.w;
    }
    return s+t;
}
#define FB_G 4
__global__ __launch_bounds__(1024) void grass_fallback(
    const float* __restrict__ inputStacks, const int* __restrict__ ops,
    const float* __restrict__ Wd, const float* __restrict__ bd,
    const float* __restrict__ Wl, const float* __restrict__ bl,
    const float* __restrict__ Wr, const float* __restrict__ br,
    const float* __restrict__ Wsd, const float* __restrict__ bsd,
    const float* __restrict__ Wsf, const float* __restrict__ bsf,
    const float* __restrict__ Wss, const float* __restrict__ bss,
    const float* __restrict__ Wbox, const float* __restrict__ bbox,
    float* __restrict__ out)
{
    __shared__ float stk[FB_G][STK_][F_];
    __shared__ float hh[FB_G][H_];
    __shared__ float boxtmp[FB_G][MAXB_][BOX_];
    __shared__ float symtmp[FB_G][MAXSY_][S_];
    const int t = threadIdx.x, b0 = blockIdx.x * FB_G;
    for (int idx = t; idx < FB_G*F_; idx += 1024) {
        int g = idx >> 9, k = idx & (F_-1);
        stk[g][0][k] = inputStacks[(size_t)(b0+g)*F_ + k];
    }
    for (int idx = t; idx < FB_G*H_; idx += 1024) hh[idx>>10][idx&(H_-1)] = 0.f;
    int sp[FB_G], bc[FB_G], sc[FB_G];
#pragma unroll
    for (int g = 0; g < FB_G; ++g) { sp[g]=1; bc[g]=0; sc[g]=0; }
    __syncthreads();
    for (int step = 0; step < L_; ++step) {
        int op[FB_G], ti[FB_G], ri[FB_G]; bool a1=false,a2=false,a0=false;
#pragma unroll
        for (int g = 0; g < FB_G; ++g) {
            op[g] = ops[(size_t)(b0+g)*L_ + (L_-1-step)];
            int tt = sp[g]-1; tt = tt<0?0:(tt>STK_-1?STK_-1:tt); ti[g]=tt;
            int rr = sp[g]; ri[g] = rr>STK_-1?STK_-1:rr;
            a1 |= (op[g]==1); a2 |= (op[g]==2); a0 |= (op[g]==0);
        }
        const float *x0=stk[0][ti[0]], *x1=stk[1][ti[1]], *x2=stk[2][ti[2]], *x3=stk[3][ti[3]];
        if (a1) {
            float r0,r1,r2,r3; fdot4(Wd+(size_t)t*F_, x0,x1,x2,x3, F_/4, r0,r1,r2,r3);
            float bb = bd[t];
            if (op[0]==1) hh[0][t]=tanhf(r0+bb); if (op[1]==1) hh[1][t]=tanhf(r1+bb);
            if (op[2]==1) hh[2][t]=tanhf(r2+bb); if (op[3]==1) hh[3][t]=tanhf(r3+bb);
        }
        if (a2) {
            float r0,r1,r2,r3; fdot4(Wsd+(size_t)t*F_, x0,x1,x2,x3, F_/4, r0,r1,r2,r3);
            float bb = bsd[t];
            if (op[0]==2) hh[0][t]=tanhf(r0+bb); if (op[1]==2) hh[1][t]=tanhf(r1+bb);
            if (op[2]==2) hh[2][t]=tanhf(r2+bb); if (op[3]==2) hh[3][t]=tanhf(r3+bb);
        }
        if (a0 && t < FB_G*BOX_) {
            int g = t / BOX_, cc = t - g*BOX_;
            if (op[g]==0) {
                float acc = fdot1(Wbox+(size_t)cc*F_, stk[g][ti[g]], F_/4);
                boxtmp[g][bc[g]][cc] = tanhf(acc + bbox[cc]);
            }
        }
        __syncthreads();
        if (a1) {
            if (t < F_) {
                float r0,r1,r2,r3; fdot4(Wl+(size_t)t*H_, hh[0],hh[1],hh[2],hh[3], H_/4, r0,r1,r2,r3);
                float bb = bl[t];
                if (op[0]==1) stk[0][ti[0]][t]=tanhf(r0+bb); if (op[1]==1) stk[1][ti[1]][t]=tanhf(r1+bb);
                if (op[2]==1) stk[2][ti[2]][t]=tanhf(r2+bb); if (op[3]==1) stk[3][ti[3]][t]=tanhf(r3+bb);
            } else {
                int m = t - F_;
                float r0,r1,r2,r3; fdot4(Wr+(size_t)m*H_, hh[0],hh[1],hh[2],hh[3], H_/4, r0,r1,r2,r3);
                float bb = br[m];
                if (op[0]==1) stk[0][ri[0]][m]=tanhf(r0+bb); if (op[1]==1) stk[1][ri[1]][m]=tanhf(r1+bb);
                if (op[2]==1) stk[2][ri[2]][m]=tanhf(r2+bb); if (op[3]==1) stk[3][ri[3]][m]=tanhf(r3+bb);
            }
        }
        if (a2) {
            if (t < F_) {
                float r0,r1,r2,r3; fdot4(Wsf+(size_t)t*H_, hh[0],hh[1],hh[2],hh[3], H_/4, r0,r1,r2,r3);
                float bb = bsf[t];
                if (op[0]==2) stk[0][ti[0]][t]=tanhf(r0+bb); if (op[1]==2) stk[1][ti[1]][t]=tanhf(r1+bb);
                if (op[2]==2) stk[2][ti[2]][t]=tanhf(r2+bb); if (op[3]==2) stk[3][ti[3]][t]=tanhf(r3+bb);
            } else if (t < F_ + FB_G*S_) {
                int idx = t - F_, g = idx >> 3, cc = idx & 7;
                if (op[g]==2) {
                    float acc = fdot1(Wss+(size_t)cc*H_, hh[g], H_/4);
                    symtmp[g][sc[g]][cc] = tanhf(acc + bss[cc]);
                }
            }
        }
        __syncthreads();
#pragma unroll
        for (int g = 0; g < FB_G; ++g) {
            if (op[g]==1) sp[g]++;
            else if (op[g]==2) sc[g]++;
            else { bc[g]++; sp[g]--; }
        }
    }
#pragma unroll
    for (int g = 0; g < FB_G; ++g) {
        int b = b0 + g;
        float* ob = out + (size_t)b * MAXB_ * BOX_;
        for (int idx = t; idx < MAXB_*BOX_; idx += 1024) {
            int jj = idx / BOX_, cc = idx - jj*BOX_;
            int e = bc[g] - 1 - jj;
            ob[idx] = (e >= 0) ? boxtmp[g][e][cc] : 0.f;
        }
        float* os = out + (size_t)B_*MAXB_*BOX_ + (size_t)b * MAXSY_ * S_;
        for (int idx = t; idx < MAXSY_*S_; idx += 1024) {
            int jj = idx >> 3, cc = idx & 7;
            int e = sc[g] - 1 - jj;
            os[idx] = (e >= 0) ? symtmp[g][e][cc] : 0.f;
        }
    }
}

// ---------------- launcher ----------------
extern "C" void kernel_launch(void* const* d_in, const int* in_sizes, int n_in,
                              void* d_out, int out_size, void* d_ws, size_t ws_size,
                              hipStream_t stream) {
    (void)in_sizes; (void)n_in;
    const float* X    = (const float*)d_in[0];
    const int*   ops  = (const int*)d_in[1];
    const float* Wd   = (const float*)d_in[2];  const float* bd   = (const float*)d_in[3];
    const float* Wl   = (const float*)d_in[4];  const float* bl   = (const float*)d_in[5];
    const float* Wr   = (const float*)d_in[6];  const float* br   = (const float*)d_in[7];
    const float* Wsd  = (const float*)d_in[8];  const float* bsd  = (const float*)d_in[9];
    const float* Wsf  = (const float*)d_in[10]; const float* bsf  = (const float*)d_in[11];
    const float* Wss  = (const float*)d_in[12]; const float* bss  = (const float*)d_in[13];
    const float* Wbox = (const float*)d_in[14]; const float* bbox = (const float*)d_in[15];
    float* out = (float*)d_out;

    if (ws_size < WS_NEED) {
        grass_fallback<<<dim3(B_/FB_G), dim3(1024), 0, stream>>>(
            X, ops, Wd, bd, Wl, bl, Wr, br, Wsd, bsd, Wsf, bsf, Wss, bss, Wbox, bbox, out);
        return;
    }
    char* ws = (char*)d_ws;
    hipMemsetAsync(d_out, 0, (size_t)out_size * sizeof(float), stream);  // zero-pad slots
    hipMemsetAsync(ws, 0, 4096, stream);   // barriers + flags + xcd slots
    grass_prep<<<dim3(512), dim3(256), 0, stream>>>(X, ops, Wd, Wl, Wr, Wsd, Wsf, Wss, Wbox, ws);
    grass_pipe<<<dim3(256), dim3(256), 0, stream>>>(bd, bl, br, bsd, bsf, bss, bbox, ws, out);
    grass_legacy<<<dim3(256), dim3(256), 0, stream>>>(ops, bd, bl, br, bsd, bsf, bss, bbox, ws, out);
}

// Round 9
// 2668.914 us; speedup vs baseline: 2.1161x; 1.0268x over previous
//
#include <hip/hip_runtime.h>
#include <stdint.h>

// ---------------- problem constants ----------------
#define B_     1024
#define F_     512
#define H_     1024
#define S_     8
#define BOX_   12
#define MAXB_  64
#define MAXSY_ 64
#define L_     126
#define STK_   3
#define NCYC_  42

typedef unsigned short u16;
typedef unsigned int   u32;
typedef unsigned long long u64;
typedef __attribute__((ext_vector_type(8))) short sh8;   // 8 bf16 (4 VGPRs)
typedef __attribute__((ext_vector_type(4))) int   i4;    // 16B payload
typedef __attribute__((ext_vector_type(4))) float f4;    // MFMA accumulator

#define MFMA16(a,b,c) __builtin_amdgcn_mfma_f32_16x16x32_bf16((a),(b),(c),0,0,0)

// HW_REG_XCC_ID (id=20), offset 0, size 32  [measured working on MI355X: learn_hip m09]
#define XCC_ID_IMM (((32 - 1) << 11) | (0 << 6) | 20)

// watchdog: poll iterations before giving up (healthy waits are <=100us; this is ~1s)
#define POLL_MAX (1 << 22)

// ---------------- ws layout (bytes) ----------------
// control area [0, 8192): [0,2048) barrier counters (gid*128B apart),
// 2048 nonuni flag, 2176 per-group fail flags, 2304 per-group xcd ids (16*32*4).
constexpr size_t O_FLAG  = 2048;
constexpr size_t O_GFAIL = 2176;
constexpr size_t O_GXCD  = 2304;
constexpr size_t PL_HF = (size_t)H_ * F_ * 2;      // 1 MB  (Wd, Wsd planes)
constexpr size_t PL_FH = (size_t)F_ * H_ * 2;      // 1 MB  (Wl, Wr, Wsf planes)
constexpr size_t PL_SS = 16384;                    // S*H*2
constexpr size_t PL_BX = 16384;                    // BOX*F*2=12288, padded
constexpr size_t O_WdHi  = 8192;
constexpr size_t O_WdLo  = O_WdHi  + PL_HF;
constexpr size_t O_WsdHi = O_WdLo  + PL_HF;
constexpr size_t O_WsdLo = O_WsdHi + PL_HF;
constexpr size_t O_WlHi  = O_WsdLo + PL_HF;
constexpr size_t O_WlLo  = O_WlHi  + PL_FH;
constexpr size_t O_WrHi  = O_WlLo  + PL_FH;
constexpr size_t O_WrLo  = O_WrHi  + PL_FH;
constexpr size_t O_WsfHi = O_WrLo  + PL_FH;
constexpr size_t O_WsfLo = O_WsfHi + PL_FH;
constexpr size_t O_WssHi = O_WsfLo + PL_FH;
constexpr size_t O_WssLo = O_WssHi + PL_SS;
constexpr size_t O_WbxHi = O_WssLo + PL_SS;
constexpr size_t O_WbxLo = O_WbxHi + PL_BX;
constexpr size_t SZ_STK  = (size_t)B_ * STK_ * F_ * 2;   // 3 MB per plane
constexpr size_t O_SHi   = O_WbxLo + PL_BX;
constexpr size_t O_SLo   = O_SHi   + SZ_STK;
constexpr size_t SZ_H    = (size_t)B_ * H_ * 2;          // 2 MB per plane
constexpr size_t O_HAHi  = O_SLo   + SZ_STK;
constexpr size_t O_HALo  = O_HAHi  + SZ_H;
constexpr size_t O_HSHi  = O_HALo  + SZ_H;
constexpr size_t O_HSLo  = O_HSHi  + SZ_H;
constexpr size_t SZ_FB   = (size_t)B_ * 512 * 2;         // 1 MB per plane
constexpr size_t O_FB0Hi = O_HSLo  + SZ_H;
constexpr size_t O_FB0Lo = O_FB0Hi + SZ_FB;
constexpr size_t O_FB1Hi = O_FB0Lo + SZ_FB;
constexpr size_t O_FB1Lo = O_FB1Hi + SZ_FB;
constexpr size_t WS_NEED = O_FB1Lo + SZ_FB;              // ~28.2 MB

// ---------------- numeric helpers ----------------
__device__ __forceinline__ float bf2float(u16 h) {
    union { u32 u; float f; } v; v.u = ((u32)h) << 16; return v.f;
}
__device__ __forceinline__ u16 bfhi_of(float f) {           // RNE fp32->bf16
    union { float f; u32 u; } v; v.f = f;
    u32 u = v.u;
    return (u16)((u + 0x7fffu + ((u >> 16) & 1u)) >> 16);
}
__device__ __forceinline__ void split2(float x, u16& hi, u16& lo) {
    hi = bfhi_of(x);
    lo = bfhi_of(x - bf2float(hi));
}

// ---------------- store helpers ----------------
// DC=true : device-coherent (sc0 sc1) -> LLC, cross-XCD safe (legacy path)
// DC=false: plain store -> this XCD's L2 (write-through L1); group-local
template<bool DC>
__device__ __forceinline__ void cst(u16* p, u16 v) {
    if (DC) asm volatile("global_store_short %0, %1, off sc0 sc1"
                         :: "v"(p), "v"((u32)v) : "memory");
    else    asm volatile("global_store_short %0, %1, off"
                         :: "v"(p), "v"((u32)v) : "memory");
}
__device__ __forceinline__ void vdrain() {
    asm volatile("s_waitcnt vmcnt(0)" ::: "memory");
}

// sc0-only batched 16B loads: bypass stale L1, read from (XCD-shared) L2. MLP=8.
__device__ __forceinline__ void cld8(i4& d0, i4& d1, i4& d2, i4& d3,
                                     i4& d4, i4& d5, i4& d6, i4& d7,
    const u16* p0, const u16* p1, const u16* p2, const u16* p3,
    const u16* p4, const u16* p5, const u16* p6, const u16* p7)
{
    asm volatile(
        "global_load_dwordx4 %0, %8, off sc0\n\t"
        "global_load_dwordx4 %1, %9, off sc0\n\t"
        "global_load_dwordx4 %2, %10, off sc0\n\t"
        "global_load_dwordx4 %3, %11, off sc0\n\t"
        "global_load_dwordx4 %4, %12, off sc0\n\t"
        "global_load_dwordx4 %5, %13, off sc0\n\t"
        "global_load_dwordx4 %6, %14, off sc0\n\t"
        "global_load_dwordx4 %7, %15, off sc0\n\t"
        "s_waitcnt vmcnt(0)"
        : "=&v"(d0),"=&v"(d1),"=&v"(d2),"=&v"(d3),
          "=&v"(d4),"=&v"(d5),"=&v"(d6),"=&v"(d7)
        : "v"(p0),"v"(p1),"v"(p2),"v"(p3),"v"(p4),"v"(p5),"v"(p6),"v"(p7));
}

// ---------------- prep: split weights + input stacks; detect pattern ----------------
__device__ void split_range(const float* __restrict__ s, u16* hi, u16* lo,
                            int n, int t0, int stride) {
    for (int i = t0; i < n; i += stride) {
        float v = s[i];
        u16 h = bfhi_of(v);
        hi[i] = h;
        lo[i] = bfhi_of(v - bf2float(h));
    }
}

__global__ void grass_prep(const float* __restrict__ X, const int* __restrict__ ops,
                           const float* __restrict__ Wd, const float* __restrict__ Wl,
                           const float* __restrict__ Wr, const float* __restrict__ Wsd,
                           const float* __restrict__ Wsf, const float* __restrict__ Wss,
                           const float* __restrict__ Wbox, char* __restrict__ ws)
{
    const int t0 = blockIdx.x * blockDim.x + threadIdx.x;
    const int st = gridDim.x * blockDim.x;
    split_range(Wd,  (u16*)(ws + O_WdHi),  (u16*)(ws + O_WdLo),  H_ * F_, t0, st);
    split_range(Wsd, (u16*)(ws + O_WsdHi), (u16*)(ws + O_WsdLo), H_ * F_, t0, st);
    split_range(Wl,  (u16*)(ws + O_WlHi),  (u16*)(ws + O_WlLo),  F_ * H_, t0, st);
    split_range(Wr,  (u16*)(ws + O_WrHi),  (u16*)(ws + O_WrLo),  F_ * H_, t0, st);
    split_range(Wsf, (u16*)(ws + O_WsfHi), (u16*)(ws + O_WsfLo), F_ * H_, t0, st);
    split_range(Wss, (u16*)(ws + O_WssHi), (u16*)(ws + O_WssLo), S_ * H_, t0, st);
    split_range(Wbox,(u16*)(ws + O_WbxHi), (u16*)(ws + O_WbxLo), BOX_ * F_, t0, st);
    u16* SHi = (u16*)(ws + O_SHi);
    u16* SLo = (u16*)(ws + O_SLo);
    for (int i = t0; i < B_ * F_; i += st) {
        int e = i >> 9, k = i & (F_ - 1);
        float v = X[i];
        u16 h = bfhi_of(v);
        size_t off = (size_t)e * STK_ * F_ + k;     // slot 0
        SHi[off] = h;
        SLo[off] = bfhi_of(v - bf2float(h));
    }
    // pattern check: stored order expects {0,2,1}[t%3]
    int* flag = (int*)(ws + O_FLAG);
    for (int i = t0; i < B_ * L_; i += st) {
        int t = i % L_;
        int tm = t % 3;
        int expect = (tm == 0) ? 0 : ((tm == 1) ? 2 : 1);
        if (ops[i] != expect) {
            __hip_atomic_store(flag, 1, __ATOMIC_RELAXED, __HIP_MEMORY_SCOPE_AGENT);
            break;
        }
    }
}

// -------- barriers (LLC / agent scope — HW-validated primitive from round 5).
// Data contract: participant drains vmcnt before signaling (stores at coherence pt).
// Pipe flavors are WATCHDOG-BOUNDED: if residency/visibility assumptions fail, blocks
// exit after ~1s instead of hanging the container (run fails with diagnostics).
__device__ __forceinline__ void gbar(int* bar, int target) {
    vdrain();
    __syncthreads();
    if (threadIdx.x == 0) {
        __hip_atomic_fetch_add(bar, 1, __ATOMIC_RELAXED, __HIP_MEMORY_SCOPE_AGENT);
        while (__hip_atomic_load(bar, __ATOMIC_RELAXED, __HIP_MEMORY_SCOPE_AGENT) < target)
            __builtin_amdgcn_s_sleep(2);
    }
    __syncthreads();
}
__device__ __forceinline__ void gbarT(int* bar, int target) {
    vdrain();
    __syncthreads();
    if (threadIdx.x == 0) {
        __hip_atomic_fetch_add(bar, 1, __ATOMIC_RELAXED, __HIP_MEMORY_SCOPE_AGENT);
        for (int it = 0; it < POLL_MAX; ++it) {
            if (__hip_atomic_load(bar, __ATOMIC_RELAXED, __HIP_MEMORY_SCOPE_AGENT) >= target) break;
            __builtin_amdgcn_s_sleep(2);
        }
    }
    __syncthreads();
}
__device__ __forceinline__ void gwaitT(int* ctr, int target) {
    if (threadIdx.x == 0) {
        for (int it = 0; it < POLL_MAX; ++it) {
            if (__hip_atomic_load(ctr, __ATOMIC_RELAXED, __HIP_MEMORY_SCOPE_AGENT) >= target) break;
            __builtin_amdgcn_s_sleep(2);
        }
    }
    __syncthreads();
}

// ---------------- activation staging, pipe (sc0/L2): 256-col chunk, 64 KB ----------
// LDS layout: 2 planes x [64 rows][256 cols] bf16, XOR-swizzled at 16B granularity.
__device__ __forceinline__ void stage256(u16* __restrict__ lds,
    const u16* __restrict__ AHi, const u16* __restrict__ ALo,
    const int* __restrict__ aOff, int kbase, int tid)
{
    const int wv = tid >> 6, lane = tid & 63;
    const int rsub = lane >> 5;              // 0/1: row within pair
    const int c8 = (lane & 31) * 8;          // elem offset of this lane's 16B chunk
    int off[8];
#pragma unroll
    for (int i = 0; i < 8; ++i) off[i] = aOff[i * 8 + wv * 2 + rsub] + kbase + c8;
    const int sw = ((wv * 2 + rsub) & 7) << 3;   // (m&7)<<3, constant per thread
    i4 d0,d1,d2,d3,d4,d5,d6,d7;
    cld8(d0,d1,d2,d3,d4,d5,d6,d7,
         AHi+off[0], AHi+off[1], AHi+off[2], AHi+off[3],
         AHi+off[4], AHi+off[5], AHi+off[6], AHi+off[7]);
#define STO(ii, dv, base) { const int m = (ii) * 8 + wv * 2 + rsub; \
                            *(i4*)((base) + m * 256 + (c8 ^ sw)) = dv; }
    STO(0,d0,lds) STO(1,d1,lds) STO(2,d2,lds) STO(3,d3,lds)
    STO(4,d4,lds) STO(5,d5,lds) STO(6,d6,lds) STO(7,d7,lds)
    cld8(d0,d1,d2,d3,d4,d5,d6,d7,
         ALo+off[0], ALo+off[1], ALo+off[2], ALo+off[3],
         ALo+off[4], ALo+off[5], ALo+off[6], ALo+off[7]);
    u16* ldsLo = lds + 64 * 256;
    STO(0,d0,ldsLo) STO(1,d1,ldsLo) STO(2,d2,ldsLo) STO(3,d3,ldsLo)
    STO(4,d4,ldsLo) STO(5,d5,ldsLo) STO(6,d6,ldsLo) STO(7,d7,ldsLo)
#undef STO
}

// ---------------- activation staging, legacy (sc0sc1/LLC): 512-col panel ----------
__device__ __forceinline__ void stageA_dc(u16* __restrict__ lds,
    const u16* __restrict__ AHi, const u16* __restrict__ ALo,
    const int* __restrict__ aOff, int kbase, int tid)
{
    const int wv = tid >> 6, lane = tid & 63;
    const int kk = kbase + lane * 8;
    int off[16];
#pragma unroll
    for (int i = 0; i < 16; ++i) off[i] = aOff[i * 4 + wv] + kk;
    u64 v[64];
#pragma unroll
    for (int i = 0; i < 16; ++i) {
        const u64* s = (const u64*)(AHi + off[i]);
        v[2 * i]     = __hip_atomic_load(s,     __ATOMIC_RELAXED, __HIP_MEMORY_SCOPE_AGENT);
        v[2 * i + 1] = __hip_atomic_load(s + 1, __ATOMIC_RELAXED, __HIP_MEMORY_SCOPE_AGENT);
    }
#pragma unroll
    for (int i = 0; i < 16; ++i) {
        const u64* s = (const u64*)(ALo + off[i]);
        v[32 + 2 * i] = __hip_atomic_load(s,     __ATOMIC_RELAXED, __HIP_MEMORY_SCOPE_AGENT);
        v[33 + 2 * i] = __hip_atomic_load(s + 1, __ATOMIC_RELAXED, __HIP_MEMORY_SCOPE_AGENT);
    }
#pragma unroll
    for (int i = 0; i < 16; ++i) {
        const int m = i * 4 + wv;
        u16* d = lds + m * 512 + ((lane * 8) ^ ((m & 7) << 3));
        ((u64*)d)[0] = v[2 * i];
        ((u64*)d)[1] = v[2 * i + 1];
        u64* d2 = (u64*)(d + 32768);
        d2[0] = v[32 + 2 * i];
        d2[1] = v[33 + 2 * i];
    }
}

// ---------------- 64x64 split-bf16 k-loop over one staged CW-col chunk ----------
// CW = LDS chunk width in elems (256 pipe / 512 legacy). wv4 0..3 = output quadrant.
template<int CW>
__device__ __forceinline__ void kloop64(const u16* __restrict__ lds,
    const u16* __restrict__ WHi, const u16* __restrict__ WLo,
    int nRow0, int Kw, int kofs, f4 c[2][2], int lane, int wv4)
{
    const int quad = lane >> 4, mr = lane & 15;
    const int mh = wv4 & 1, nh = (wv4 >> 1) & 1;
    const int m0 = (mh * 2) * 16 + mr, m1 = m0 + 16;
    const int n0 = nRow0 + (nh * 2) * 16 + mr, n1 = n0 + 16;
    const u16* b0h = WHi + (size_t)n0 * Kw + kofs;
    const u16* b1h = WHi + (size_t)n1 * Kw + kofs;
    const u16* b0l = WLo + (size_t)n0 * Kw + kofs;
    const u16* b1l = WLo + (size_t)n1 * Kw + kofs;
    const int sw = (m0 & 7) << 3;              // (m1&7)==(m0&7): same swizzle
    const u16* A0h = lds + m0 * CW;
    const u16* A1h = lds + m1 * CW;
#pragma unroll 2
    for (int kb = 0; kb < CW; kb += 64) {
        const int k0 = kb + quad * 8, k1 = k0 + 32;
        const int x0 = k0 ^ sw, x1 = k1 ^ sw;
        sh8 B0H0 = *(const sh8*)(b0h + k0), B1H0 = *(const sh8*)(b1h + k0);
        sh8 B0L0 = *(const sh8*)(b0l + k0), B1L0 = *(const sh8*)(b1l + k0);
        sh8 B0H1 = *(const sh8*)(b0h + k1), B1H1 = *(const sh8*)(b1h + k1);
        sh8 B0L1 = *(const sh8*)(b0l + k1), B1L1 = *(const sh8*)(b1l + k1);
        sh8 A0H0 = *(const sh8*)(A0h + x0);
        sh8 A1H0 = *(const sh8*)(A1h + x0);
        sh8 A0L0 = *(const sh8*)(A0h + 64 * CW + x0);
        sh8 A1L0 = *(const sh8*)(A1h + 64 * CW + x0);
        sh8 A0H1 = *(const sh8*)(A0h + x1);
        sh8 A1H1 = *(const sh8*)(A1h + x1);
        sh8 A0L1 = *(const sh8*)(A0h + 64 * CW + x1);
        sh8 A1L1 = *(const sh8*)(A1h + 64 * CW + x1);
        c[0][0]=MFMA16(A0H0,B0H0,c[0][0]); c[0][1]=MFMA16(A0H0,B1H0,c[0][1]);
        c[1][0]=MFMA16(A1H0,B0H0,c[1][0]); c[1][1]=MFMA16(A1H0,B1H0,c[1][1]);
        c[0][0]=MFMA16(A0H0,B0L0,c[0][0]); c[0][1]=MFMA16(A0H0,B1L0,c[0][1]);
        c[1][0]=MFMA16(A1H0,B0L0,c[1][0]); c[1][1]=MFMA16(A1H0,B1L0,c[1][1]);
        c[0][0]=MFMA16(A0L0,B0H0,c[0][0]); c[0][1]=MFMA16(A0L0,B1H0,c[0][1]);
        c[1][0]=MFMA16(A1L0,B0H0,c[1][0]); c[1][1]=MFMA16(A1L0,B1H0,c[1][1]);
        c[0][0]=MFMA16(A0H1,B0H1,c[0][0]); c[0][1]=MFMA16(A0H1,B1H1,c[0][1]);
        c[1][0]=MFMA16(A1H1,B0H1,c[1][0]); c[1][1]=MFMA16(A1H1,B1H1,c[1][1]);
        c[0][0]=MFMA16(A0H1,B0L1,c[0][0]); c[0][1]=MFMA16(A0H1,B1L1,c[0][1]);
        c[1][0]=MFMA16(A1H1,B0L1,c[1][0]); c[1][1]=MFMA16(A1H1,B1L1,c[1][1]);
        c[0][0]=MFMA16(A0L1,B0H1,c[0][0]); c[0][1]=MFMA16(A0L1,B1H1,c[0][1]);
        c[1][0]=MFMA16(A1L1,B0H1,c[1][0]); c[1][1]=MFMA16(A1L1,B1H1,c[1][1]);
    }
}

// 64 x (<=16): wave wv (0..3) owns rows wv*16..+16.
template<int CW>
__device__ __forceinline__ void kloop16(const u16* __restrict__ lds,
    const u16* __restrict__ WHi, const u16* __restrict__ WLo,
    int nValid, int Kw, int kofs, f4& c, int lane, int wv)
{
    const int quad = lane >> 4, mr = lane & 15;
    const int m = wv * 16 + mr;
    const int sm = (m & 7) << 3;
    const u16* Am = lds + m * CW;
    const bool nb = (mr < nValid);
    const u16* bh = WHi + (size_t)mr * Kw + kofs;
    const u16* bl = WLo + (size_t)mr * Kw + kofs;
#pragma unroll 2
    for (int kb = 0; kb < CW; kb += 64) {
        const int k0 = kb + quad * 8, k1 = k0 + 32;
        const int x0 = k0 ^ sm, x1 = k1 ^ sm;
        sh8 bH0 = {0,0,0,0,0,0,0,0}, bL0 = {0,0,0,0,0,0,0,0};
        sh8 bH1 = {0,0,0,0,0,0,0,0}, bL1 = {0,0,0,0,0,0,0,0};
        if (nb) {
            bH0 = *(const sh8*)(bh + k0); bL0 = *(const sh8*)(bl + k0);
            bH1 = *(const sh8*)(bh + k1); bL1 = *(const sh8*)(bl + k1);
        }
        sh8 aH0 = *(const sh8*)(Am + x0);
        sh8 aL0 = *(const sh8*)(Am + 64 * CW + x0);
        sh8 aH1 = *(const sh8*)(Am + x1);
        sh8 aL1 = *(const sh8*)(Am + 64 * CW + x1);
        c = MFMA16(aH0, bH0, c);
        c = MFMA16(aH0, bL0, c);
        c = MFMA16(aL0, bH0, c);
        c = MFMA16(aH1, bH1, c);
        c = MFMA16(aH1, bL1, c);
        c = MFMA16(aL1, bH1, c);
    }
}

__device__ __forceinline__ void zacc(f4 c[2][2]) {
    f4 z = {0.f, 0.f, 0.f, 0.f};
    c[0][0] = z; c[0][1] = z; c[1][0] = z; c[1][1] = z;
}

// legacy: stage(sc1, 512-panel) + k-loop
__device__ __forceinline__ void gemmK(u16* __restrict__ Ab,
    const u16* __restrict__ AHi, const u16* __restrict__ ALo, const int* __restrict__ aOff,
    const u16* __restrict__ WHi, const u16* __restrict__ WLo, int nRow0, int Kw,
    f4 c[2][2], int tid, int lane, int wv)
{
    zacc(c);
    for (int h = 0; h < Kw; h += 512) {
        __syncthreads();
        stageA_dc(Ab, AHi, ALo, aOff, h, tid);
        __syncthreads();
        kloop64<512>(Ab, WHi, WLo, nRow0, Kw, h, c, lane, wv);
    }
}
__device__ __forceinline__ void gemmK16(u16* __restrict__ Ab,
    const u16* __restrict__ AHi, const u16* __restrict__ ALo, const int* __restrict__ aOff,
    const u16* __restrict__ WHi, const u16* __restrict__ WLo, int nValid, int Kw,
    f4& c, int tid, int lane, int wv)
{
    f4 z = {0.f, 0.f, 0.f, 0.f};
    c = z;
    for (int h = 0; h < Kw; h += 512) {
        __syncthreads();
        stageA_dc(Ab, AHi, ALo, aOff, h, tid);
        __syncthreads();
        kloop16<512>(Ab, WHi, WLo, nValid, Kw, h, c, lane, wv);
    }
}

// pipe: one 64-col output tile accumulated over 256-col staged chunks (sc0 stage)
__device__ __forceinline__ void pipe_gemm64(u16* __restrict__ Ab,
    const u16* __restrict__ AHi, const u16* __restrict__ ALo, const int* __restrict__ aOff,
    const u16* __restrict__ WHi, const u16* __restrict__ WLo, int col0, int Kw,
    f4 c[2][2], int tid, int lane, int wv)
{
    zacc(c);
    for (int h = 0; h < Kw; h += 256) {
        __syncthreads();
        stage256(Ab, AHi, ALo, aOff, h, tid);
        __syncthreads();
        kloop64<256>(Ab, WHi, WLo, col0, Kw, h, c, lane, wv);
    }
}

// ---------------- epilogues (C/D map: col=lane&15, row=(lane>>4)*4+reg) ----------
template<bool DC>
__device__ __forceinline__ void ep_h(const f4 c[2][2], const float* __restrict__ bias,
                                     int colBase, int e0, u16* DHi, u16* DLo,
                                     int lane, int wv4)
{
    const int quad = lane >> 4, mr = lane & 15;
    const int mh = wv4 & 1, nh = (wv4 >> 1) & 1;
#pragma unroll
    for (int mi = 0; mi < 2; ++mi)
#pragma unroll
    for (int ni = 0; ni < 2; ++ni)
#pragma unroll
    for (int r = 0; r < 4; ++r) {
        int mm = (mh * 2 + mi) * 16 + quad * 4 + r;
        int nn = (nh * 2 + ni) * 16 + mr;
        float v = tanhf(c[mi][ni][r] + bias[colBase + nn]);
        u16 hi, lo; split2(v, hi, lo);
        size_t off = (size_t)(e0 + mm) * H_ + colBase + nn;
        cst<DC>(DHi + off, hi);
        cst<DC>(DLo + off, lo);
    }
}

template<bool DC>
__device__ __forceinline__ void ep_slot(const f4 c[2][2], const float* __restrict__ bias,
                                        int colBase, int slot, int e0,
                                        u16* SHi, u16* SLo, int lane, int wv4)
{
    const int quad = lane >> 4, mr = lane & 15;
    const int mh = wv4 & 1, nh = (wv4 >> 1) & 1;
#pragma unroll
    for (int mi = 0; mi < 2; ++mi)
#pragma unroll
    for (int ni = 0; ni < 2; ++ni)
#pragma unroll
    for (int r = 0; r < 4; ++r) {
        int mm = (mh * 2 + mi) * 16 + quad * 4 + r;
        int nn = (nh * 2 + ni) * 16 + mr;
        float v = tanhf(c[mi][ni][r] + bias[colBase + nn]);
        u16 hi, lo; split2(v, hi, lo);
        size_t off = ((size_t)(e0 + mm) * STK_ + slot) * F_ + colBase + nn;
        cst<DC>(SHi + off, hi);
        cst<DC>(SLo + off, lo);
    }
}

template<bool DC>
__device__ __forceinline__ void ep_fb(const f4 c[2][2], const float* __restrict__ bias,
                                      int colBase, int e0, u16* FHi, u16* FLo,
                                      int lane, int wv4)
{
    const int quad = lane >> 4, mr = lane & 15;
    const int mh = wv4 & 1, nh = (wv4 >> 1) & 1;
#pragma unroll
    for (int mi = 0; mi < 2; ++mi)
#pragma unroll
    for (int ni = 0; ni < 2; ++ni)
#pragma unroll
    for (int r = 0; r < 4; ++r) {
        int mm = (mh * 2 + mi) * 16 + quad * 4 + r;
        int nn = (nh * 2 + ni) * 16 + mr;
        float v = tanhf(c[mi][ni][r] + bias[colBase + nn]);
        u16 hi, lo; split2(v, hi, lo);
        size_t off = (size_t)(e0 + mm) * 512 + colBase + nn;
        cst<DC>(FHi + off, hi);
        cst<DC>(FLo + off, lo);
    }
}

template<bool DC>
__device__ __forceinline__ void ep_stack(const f4 c[2][2], const float* __restrict__ bias,
                                         int colBase, int opSel, bool useRi, int tix, int e0,
                                         const unsigned char* opsL, const int* spA,
                                         u16* SHi, u16* SLo, int lane, int wv)
{
    const int quad = lane >> 4, mr = lane & 15;
    const int mh = wv & 1, nh = (wv >> 1) & 1;
#pragma unroll
    for (int mi = 0; mi < 2; ++mi)
#pragma unroll
    for (int ni = 0; ni < 2; ++ni)
#pragma unroll
    for (int r = 0; r < 4; ++r) {
        int mm = (mh * 2 + mi) * 16 + quad * 4 + r;
        int nn = (nh * 2 + ni) * 16 + mr;
        if (opsL[mm * L_ + tix] != opSel) continue;
        int sp = spA[mm];
        int slot = useRi ? sp : sp - 1;
        slot = slot < 0 ? 0 : (slot > STK_ - 1 ? STK_ - 1 : slot);
        float v = tanhf(c[mi][ni][r] + bias[colBase + nn]);
        u16 hi, lo; split2(v, hi, lo);
        size_t off = ((size_t)(e0 + mm) * STK_ + slot) * F_ + colBase + nn;
        cst<DC>(SHi + off, hi);
        cst<DC>(SLo + off, lo);
    }
}

__device__ __forceinline__ void ep_small(const f4& c, const float* __restrict__ bias,
                                         int nValid, int opSel, int tix, int e0,
                                         const unsigned char* opsL, const int* eCnt, const int* eTot,
                                         float* __restrict__ outBase, int rowStride, int ncols,
                                         int lane, int wv)
{
    const int nn = lane & 15;
    if (nn >= nValid) return;
#pragma unroll
    for (int r = 0; r < 4; ++r) {
        int mm = wv * 16 + (lane >> 4) * 4 + r;
        if (opsL[mm * L_ + tix] != opSel) continue;
        int slot = eTot[mm] - 1 - eCnt[mm];
        if (slot < 0 || slot >= 64) continue;
        float v = tanhf(c[r] + bias[nn]);
        outBase[(size_t)(e0 + mm) * rowStride + slot * ncols + nn] = v;
    }
}

__device__ __forceinline__ void ep_small_u(const f4& c, const float* __restrict__ bias,
                                           int nValid, int slot, int e0,
                                           float* __restrict__ outBase, int rowStride, int ncols,
                                           int lane, int wv)
{
    const int nn = lane & 15;
    if (nn >= nValid) return;
#pragma unroll
    for (int r = 0; r < 4; ++r) {
        int mm = wv * 16 + (lane >> 4) * 4 + r;
        outBase[(size_t)(e0 + mm) * rowStride + slot * ncols + nn] = tanhf(c[r] + bias[nn]);
    }
}

// ---------------- pipe kernel: 16 groups x (16 chain + 16 side) x 256 threads --------
// blockIdx = role*16 + gid => all 32 blocks of a group share (blockIdx mod 8) = gid mod 8
// => same XCD under round-robin dispatch (verified at runtime; mismatch -> legacy).
// 66 KB LDS + <=256 VGPR (launch_bounds(256,2)) => 2 blocks/CU = 2 waves/SIMD (TLP).
// Barriers: LLC agent-scope (HW-validated in round 5) with watchdog-bounded polls.
__global__ __launch_bounds__(256, 2) void grass_pipe(
    const float* __restrict__ bd, const float* __restrict__ bl, const float* __restrict__ br,
    const float* __restrict__ bsd, const float* __restrict__ bsf, const float* __restrict__ bss,
    const float* __restrict__ bbox,
    char* __restrict__ ws, float* __restrict__ out)
{
    if (__hip_atomic_load((int*)(ws + O_FLAG), __ATOMIC_RELAXED, __HIP_MEMORY_SCOPE_AGENT))
        return;   // non-uniform program: legacy kernel handles everything

    const int tid  = threadIdx.x;
    const int lane = tid & 63, wv = tid >> 6;   // wv 0..3
    const int j    = blockIdx.x >> 4;           // role: 0..15 chain, 16..31 side
    const int gid  = blockIdx.x & 15;           // group (64 batch rows)
    const int e0   = gid * 64;

    const u16* WdHi  = (const u16*)(ws + O_WdHi);
    const u16* WdLo  = (const u16*)(ws + O_WdLo);
    const u16* WsdHi = (const u16*)(ws + O_WsdHi);
    const u16* WsdLo = (const u16*)(ws + O_WsdLo);
    const u16* WlHi  = (const u16*)(ws + O_WlHi);
    const u16* WlLo  = (const u16*)(ws + O_WlLo);
    const u16* WrHi  = (const u16*)(ws + O_WrHi);
    const u16* WrLo  = (const u16*)(ws + O_WrLo);
    const u16* WsfHi = (const u16*)(ws + O_WsfHi);
    const u16* WsfLo = (const u16*)(ws + O_WsfLo);
    const u16* WssHi = (const u16*)(ws + O_WssHi);
    const u16* WssLo = (const u16*)(ws + O_WssLo);
    const u16* WbxHi = (const u16*)(ws + O_WbxHi);
    const u16* WbxLo = (const u16*)(ws + O_WbxLo);
    u16* SHi  = (u16*)(ws + O_SHi);
    u16* SLo  = (u16*)(ws + O_SLo);
    u16* HAHi = (u16*)(ws + O_HAHi);
    u16* HALo = (u16*)(ws + O_HALo);
    u16* HSHi = (u16*)(ws + O_HSHi);
    u16* HSLo = (u16*)(ws + O_HSLo);
    u16* FB0Hi = (u16*)(ws + O_FB0Hi);
    u16* FB0Lo = (u16*)(ws + O_FB0Lo);
    u16* FB1Hi = (u16*)(ws + O_FB1Hi);
    u16* FB1Lo = (u16*)(ws + O_FB1Lo);
    int* cbar = (int*)ws + gid * 32;        // chain barrier (16 blocks)
    int* sbar = cbar + 1;                   // side barrier (16 blocks)
    int* pbar = cbar + 3;                   // prologue barrier (32 blocks)
    int* gx   = (int*)(ws + O_GXCD) + gid * 32;
    int* gf   = (int*)(ws + O_GFAIL) + gid;

    float* outB = out;
    float* outS = out + (size_t)B_ * MAXB_ * BOX_;

    __shared__ __align__(16) u16 Abuf[2 * 64 * 256];     // 64 KB staged A chunk
    __shared__ int aS0[64], aR1[64], aR2[64], aHH[64], aFB[64];

    if (tid < 64) {
        aS0[tid] = ((e0 + tid) * STK_ + 0) * F_;
        aR1[tid] = ((e0 + tid) * STK_ + 1) * F_;
        aR2[tid] = ((e0 + tid) * STK_ + 2) * F_;
        aHH[tid] = (e0 + tid) * H_;
        aFB[tid] = (e0 + tid) * 512;
    }

    // ---- XCD homogeneity check (correctness gate for L2 data exchange) ----
    const int myxcd = (int)(__builtin_amdgcn_s_getreg(XCC_ID_IMM) & 0xf);
    if (tid == 0)
        __hip_atomic_store(gx + j, myxcd, __ATOMIC_RELAXED, __HIP_MEMORY_SCOPE_AGENT);
    gbarT(pbar, 32);
    if (tid < 32) {
        int ox = __hip_atomic_load(gx + tid, __ATOMIC_RELAXED, __HIP_MEMORY_SCOPE_AGENT);
        if (ox != myxcd)
            __hip_atomic_store(gf, 1, __ATOMIC_RELAXED, __HIP_MEMORY_SCOPE_AGENT);
    }
    gbarT(pbar, 64);
    if (__hip_atomic_load(gf, __ATOMIC_RELAXED, __HIP_MEMORY_SCOPE_AGENT))
        return;   // group not on one XCD -> legacy kernel will process it

    f4 cA[2][2];
    f4 cs;

    if (j < 16) {
        // ===== chain: op1 only. 64 output cols per block. =====
        for (int cyc = 0; cyc < NCYC_; ++cyc) {
            // p1: HA = tanh(Wd @ slot0 + bd), cols j*64
            pipe_gemm64(Abuf, SHi, SLo, aS0, WdHi, WdLo, j * 64, F_, cA, tid, lane, wv);
            ep_h<false>(cA, bd, j * 64, e0, HAHi, HALo, lane, wv);
            gbarT(cbar, 16 * (2 * cyc + 1));
            // p2: l -> slot0 (j<8), r -> rotating slot (j>=8)
            if (j < 8) {
                pipe_gemm64(Abuf, HAHi, HALo, aHH, WlHi, WlLo, j * 64, H_, cA, tid, lane, wv);
                ep_slot<false>(cA, bl, j * 64, 0, e0, SHi, SLo, lane, wv);
            } else {
                const int rs = 1 + (cyc & 1);
                pipe_gemm64(Abuf, HAHi, HALo, aHH, WrHi, WrLo, (j - 8) * 64, H_, cA, tid, lane, wv);
                if (cyc >= 2) gwaitT(sbar, 16 * (2 * (cyc - 2) + 1));  // r-slot WAR vs side(cyc-2)
                ep_slot<false>(cA, br, (j - 8) * 64, rs, e0, SHi, SLo, lane, wv);
            }
            gbarT(cbar, 16 * (2 * cyc + 2));
        }
    } else {
        // ===== side: op2 + op0, lagging the chain by one phase =====
        const int role = j - 16;
        for (int cyc = 0; cyc < NCYC_; ++cyc) {
            gwaitT(cbar, 16 * (2 * cyc + 2));          // r(cyc) ready
            const int* aR = (cyc & 1) ? aR2 : aR1;
            // p1: HS = tanh(Wsd @ r + bsd), cols role*64
            pipe_gemm64(Abuf, SHi, SLo, aR, WsdHi, WsdLo, role * 64, F_, cA, tid, lane, wv);
            ep_h<false>(cA, bsd, role * 64, e0, HSHi, HSLo, lane, wv);
            gbarT(sbar, 16 * (2 * cyc + 1));
            // p2: f (roles 0-7), sym (role 8), box(cyc-1) (role 9), idle (10-15)
            if (role < 8) {
                u16* FH = (cyc & 1) ? FB1Hi : FB0Hi;
                u16* FL = (cyc & 1) ? FB1Lo : FB0Lo;
                pipe_gemm64(Abuf, HSHi, HSLo, aHH, WsfHi, WsfLo, role * 64, H_, cA, tid, lane, wv);
                ep_fb<false>(cA, bsf, role * 64, e0, FH, FL, lane, wv);
            } else if (role == 8) {
                f4 z = {0.f, 0.f, 0.f, 0.f}; cs = z;
                for (int h = 0; h < H_; h += 256) {
                    __syncthreads();
                    stage256(Abuf, HSHi, HSLo, aHH, h, tid);
                    __syncthreads();
                    kloop16<256>(Abuf, WssHi, WssLo, S_, H_, h, cs, lane, wv);
                }
                ep_small_u(cs, bss, S_, NCYC_ - 1 - cyc, e0, outS, MAXSY_ * S_, S_, lane, wv);
            } else if (role == 9 && cyc >= 1) {
                const u16* FH = ((cyc - 1) & 1) ? FB1Hi : FB0Hi;
                const u16* FL = ((cyc - 1) & 1) ? FB1Lo : FB0Lo;
                f4 z = {0.f, 0.f, 0.f, 0.f}; cs = z;
                for (int h = 0; h < 512; h += 256) {
                    __syncthreads();
                    stage256(Abuf, FH, FL, aFB, h, tid);
                    __syncthreads();
                    kloop16<256>(Abuf, WbxHi, WbxLo, BOX_, 512, h, cs, lane, wv);
                }
                ep_small_u(cs, bbox, BOX_, NCYC_ - (cyc - 1) - 1, e0, outB, MAXB_ * BOX_, BOX_, lane, wv);
            }
            gbarT(sbar, 16 * (2 * cyc + 2));
        }
        if (role == 9) {   // final box(41): f(41) guarded by the last sbar
            const u16* FH = ((NCYC_ - 1) & 1) ? FB1Hi : FB0Hi;
            const u16* FL = ((NCYC_ - 1) & 1) ? FB1Lo : FB0Lo;
            f4 z = {0.f, 0.f, 0.f, 0.f}; cs = z;
            for (int h = 0; h < 512; h += 256) {
                __syncthreads();
                stage256(Abuf, FH, FL, aFB, h, tid);
                __syncthreads();
                kloop16<256>(Abuf, WbxHi, WbxLo, BOX_, 512, h, cs, lane, wv);
            }
            ep_small_u(cs, bbox, BOX_, 0, e0, outB, MAXB_ * BOX_, BOX_, lane, wv);
        }
    }
}

// ---------------- legacy general kernel (non-uniform programs OR failed groups) ----
__global__ __launch_bounds__(256, 2) void grass_legacy(
    const int* __restrict__ ops,
    const float* __restrict__ bd, const float* __restrict__ bl, const float* __restrict__ br,
    const float* __restrict__ bsd, const float* __restrict__ bsf, const float* __restrict__ bss,
    const float* __restrict__ bbox,
    char* __restrict__ ws, float* __restrict__ out)
{
    const int tid  = threadIdx.x;
    const int lane = tid & 63, wv = tid >> 6;
    const int gid  = blockIdx.x >> 4;
    const int j    = blockIdx.x & 15;
    const int e0   = gid * 64;

    {
        int nonuni = __hip_atomic_load((int*)(ws + O_FLAG), __ATOMIC_RELAXED, __HIP_MEMORY_SCOPE_AGENT);
        int gfl = __hip_atomic_load((int*)(ws + O_GFAIL) + gid, __ATOMIC_RELAXED, __HIP_MEMORY_SCOPE_AGENT);
        if (!nonuni && !gfl) return;   // pipe kernel already did this group
    }

    const u16* WdHi  = (const u16*)(ws + O_WdHi);
    const u16* WdLo  = (const u16*)(ws + O_WdLo);
    const u16* WsdHi = (const u16*)(ws + O_WsdHi);
    const u16* WsdLo = (const u16*)(ws + O_WsdLo);
    const u16* WlHi  = (const u16*)(ws + O_WlHi);
    const u16* WlLo  = (const u16*)(ws + O_WlLo);
    const u16* WrHi  = (const u16*)(ws + O_WrHi);
    const u16* WrLo  = (const u16*)(ws + O_WrLo);
    const u16* WsfHi = (const u16*)(ws + O_WsfHi);
    const u16* WsfLo = (const u16*)(ws + O_WsfLo);
    const u16* WssHi = (const u16*)(ws + O_WssHi);
    const u16* WssLo = (const u16*)(ws + O_WssLo);
    const u16* WbxHi = (const u16*)(ws + O_WbxHi);
    const u16* WbxLo = (const u16*)(ws + O_WbxLo);
    u16* SHi  = (u16*)(ws + O_SHi);
    u16* SLo  = (u16*)(ws + O_SLo);
    u16* HAHi = (u16*)(ws + O_HAHi);
    u16* HALo = (u16*)(ws + O_HALo);
    u16* HSHi = (u16*)(ws + O_HSHi);
    u16* HSLo = (u16*)(ws + O_HSLo);
    int* bar = (int*)ws + gid * 32 + 2;   // distinct from pipe counters

    float* outB = out;
    float* outS = out + (size_t)B_ * MAXB_ * BOX_;

    __shared__ __align__(16) u16 Abuf[2 * 64 * 512];
    __shared__ unsigned char opsL[64 * L_];
    __shared__ int spA[64], beA[64], seA[64], beF[64], seF[64];
    __shared__ int aStk[64], aHH[64];
    __shared__ int sInfo[2];

    for (int idx = tid; idx < 64 * L_; idx += 256) {
        int e = idx / L_, t = idx - e * L_;
        opsL[idx] = (unsigned char)ops[(size_t)(e0 + e) * L_ + t];
    }
    __syncthreads();
    if (tid < 64) {
        spA[tid] = 1; beA[tid] = 0; seA[tid] = 0;
        int cb = 0, cs2 = 0;
        for (int t = 0; t < L_; ++t) {
            int o = opsL[tid * L_ + t];
            cb += (o == 0); cs2 += (o == 2);
        }
        beF[tid] = cb; seF[tid] = cs2;
        aHH[tid]  = (e0 + tid) * H_;
        aStk[tid] = ((e0 + tid) * STK_ + 0) * F_;
    }
    __syncthreads();

    int epoch = 0;
    f4 c[2][2];
    f4 cs;

    for (int step = 0; step < L_; ++step) {
        const int tix = L_ - 1 - step;
        if (wv == 0) {
            int o  = opsL[lane * L_ + tix];
            int sp = spA[lane];
            unsigned long long bo = __ballot(o  == opsL[0 * L_ + tix]);
            unsigned long long bs = __ballot(sp == spA[0]);
            if (lane == 0) {
                sInfo[0] = o;
                sInfo[1] = (bo == ~0ull && bs == ~0ull) ? 1 : 0;
            }
        }
        __syncthreads();
        const int opU = sInfo[0], uni = sInfo[1];

        if (uni) {
            if (opU == 1) {
                gemmK(Abuf, SHi, SLo, aStk, WdHi, WdLo, j * 64, F_, c, tid, lane, wv);
                ep_h<true>(c, bd, j * 64, e0, HAHi, HALo, lane, wv);
                ++epoch; gbar(bar, 16 * epoch);
                {
                    const u16* W2H = (j < 8) ? WlHi : WrHi;
                    const u16* W2L = (j < 8) ? WlLo : WrLo;
                    const float* b2 = (j < 8) ? bl : br;
                    gemmK(Abuf, HAHi, HALo, aHH, W2H, W2L, (j & 7) * 64, H_, c, tid, lane, wv);
                    ep_stack<true>(c, b2, (j & 7) * 64, 1, j >= 8, tix, e0, opsL, spA, SHi, SLo, lane, wv);
                }
                ++epoch; gbar(bar, 16 * epoch);
            } else if (opU == 2) {
                gemmK(Abuf, SHi, SLo, aStk, WsdHi, WsdLo, j * 64, F_, c, tid, lane, wv);
                ep_h<true>(c, bsd, j * 64, e0, HAHi, HALo, lane, wv);
                ++epoch; gbar(bar, 16 * epoch);
                if (j < 8) {
                    gemmK(Abuf, HAHi, HALo, aHH, WsfHi, WsfLo, j * 64, H_, c, tid, lane, wv);
                    ep_stack<true>(c, bsf, j * 64, 2, false, tix, e0, opsL, spA, SHi, SLo, lane, wv);
                } else if (j == 8) {
                    gemmK16(Abuf, HAHi, HALo, aHH, WssHi, WssLo, S_, H_, cs, tid, lane, wv);
                    ep_small(cs, bss, S_, 2, tix, e0, opsL, seA, seF, outS, MAXSY_ * S_, S_, lane, wv);
                }
                ++epoch; gbar(bar, 16 * epoch);
            } else {
                if (j == 0) {
                    gemmK16(Abuf, SHi, SLo, aStk, WbxHi, WbxLo, BOX_, F_, cs, tid, lane, wv);
                    ep_small(cs, bbox, BOX_, 0, tix, e0, opsL, beA, beF, outB, MAXB_ * BOX_, BOX_, lane, wv);
                }
            }
        } else {
            gemmK(Abuf, SHi, SLo, aStk, WdHi, WdLo, j * 64, F_, c, tid, lane, wv);
            ep_h<true>(c, bd, j * 64, e0, HAHi, HALo, lane, wv);
            gemmK(Abuf, SHi, SLo, aStk, WsdHi, WsdLo, j * 64, F_, c, tid, lane, wv);
            ep_h<true>(c, bsd, j * 64, e0, HSHi, HSLo, lane, wv);
            if (j == 0) {
                gemmK16(Abuf, SHi, SLo, aStk, WbxHi, WbxLo, BOX_, F_, cs, tid, lane, wv);
                ep_small(cs, bbox, BOX_, 0, tix, e0, opsL, beA, beF, outB, MAXB_ * BOX_, BOX_, lane, wv);
            }
            ++epoch; gbar(bar, 16 * epoch);
            if (j < 8) {
                gemmK(Abuf, HAHi, HALo, aHH, WlHi, WlLo, j * 64, H_, c, tid, lane, wv);
                ep_stack<true>(c, bl, j * 64, 1, false, tix, e0, opsL, spA, SHi, SLo, lane, wv);
                gemmK(Abuf, HSHi, HSLo, aHH, WsfHi, WsfLo, j * 64, H_, c, tid, lane, wv);
                ep_stack<true>(c, bsf, j * 64, 2, false, tix, e0, opsL, spA, SHi, SLo, lane, wv);
            } else {
                gemmK(Abuf, HAHi, HALo, aHH, WrHi, WrLo, (j - 8) * 64, H_, c, tid, lane, wv);
                ep_stack<true>(c, br, (j & 7) * 64, 1, true, tix, e0, opsL, spA, SHi, SLo, lane, wv);
                if (j == 8) {
                    gemmK16(Abuf, HSHi, HSLo, aHH, WssHi, WssLo, S_, H_, cs, tid, lane, wv);
                    ep_small(cs, bss, S_, 2, tix, e0, opsL, seA, seF, outS, MAXSY_ * S_, S_, lane, wv);
                }
            }
            ++epoch; gbar(bar, 16 * epoch);
        }

        __syncthreads();
        if (tid < 64) {
            int o = opsL[tid * L_ + tix];
            if (o == 1)      spA[tid]++;
            else if (o == 2) seA[tid]++;
            else           { beA[tid]++; spA[tid]--; }
            int sp = spA[tid];
            int ti = sp - 1; ti = ti < 0 ? 0 : (ti > STK_ - 1 ? STK_ - 1 : ti);
            aStk[tid] = ((e0 + tid) * STK_ + ti) * F_;
        }
        __syncthreads();
    }
}

// ======================= fallback (fp32 kernel) =======================
__device__ __forceinline__ void fdot4(const float* __restrict__ row,
                                      const float* __restrict__ x0, const float* __restrict__ x1,
                                      const float* __restrict__ x2, const float* __restrict__ x3,
                                      int K4, float& r0, float& r1, float& r2, float& r3)
{
    const float4* r  = (const float4*)row;
    const float4* p0 = (const float4*)x0; const float4* p1 = (const float4*)x1;
    const float4* p2 = (const float4*)x2; const float4* p3 = (const float4*)x3;
    float s0=0.f,s1=0.f,s2=0.f,s3=0.f,t0=0.f,t1=0.f,t2=0.f,t3=0.f;
    for (int i = 0; i < K4; i += 2) {
        float4 w0 = r[i], w1 = r[i+1]; float4 v;
        v=p0[i]; s0+=w0.x*v.x; s0+=w0.y*v.y; s0+=w0.z*v.z; s0+=w0.w*v.w;
        v=p0[i+1]; t0+=w1.x*v.x; t0+=w1.y*v.y; t0+=w1.z*v.z; t0+=w1.w*v.w;
        v=p1[i]; s1+=w0.x*v.x; s1+=w0.y*v.y; s1+=w0.z*v.z; s1+=w0.w*v.w;
        v=p1[i+1]; t1+=w1.x*v.x; t1+=w1.y*v.y; t1+=w1.z*v.z; t1+=w1.w*v.w;
        v=p2[i]; s2+=w0.x*v.x; s2+=w0.y*v.y; s2+=w0.z*v.z; s2+=w0.w*v.w;
        v=p2[i+1]; t2+=w1.x*v.x; t2+=w1.y*v.y; t2+=w1.z*v.z; t2+=w1.w*v.w;
        v=p3[i]; s3+=w0.x*v.x; s3+=w0.y*v.y; s3+=w0.z*v.z; s3+=w0.w*v.w;
        v=p3[i+1]; t3+=w1.x*v.x; t3+=w1.y*v.y; t3+=w1.z*v.z; t3+=w1.w*v.w;
    }
    r0=s0+t0; r1=s1+t1; r2=s2+t2; r3=s3+t3;
}
__device__ __forceinline__ float fdot1(const float* __restrict__ row,
                                       const float* __restrict__ x, int K4)
{
    const float4* r = (const float4*)row; const float4* p = (const float4*)x;
    float s=0.f,t=0.f;
    for (int i = 0; i < K4; i += 2) {
        float4 w0=r[i], v0=p[i], w1=r[i+1], v1=p[i+1];
        s+=w0.x*v0.x; s+=w0.y*v0.y; s+=w0.z*v0.z; s+=w0.w*v0.w;
        t+=w1.x*v1.x; t+=w1.y*v1.y; t+=w1.z*v1.z; t+=w1.w*v1.w;
    }
    return s+t;
}
#define FB_G 4
__global__ __launch_bounds__(1024) void grass_fallback(
    const float* __restrict__ inputStacks, const int* __restrict__ ops,
    const float* __restrict__ Wd, const float* __restrict__ bd,
    const float* __restrict__ Wl, const float* __restrict__ bl,
    const float* __restrict__ Wr, const float* __restrict__ br,
    const float* __restrict__ Wsd, const float* __restrict__ bsd,
    const float* __restrict__ Wsf, const float* __restrict__ bsf,
    const float* __restrict__ Wss, const float* __restrict__ bss,
    const float* __restrict__ Wbox, const float* __restrict__ bbox,
    float* __restrict__ out)
{
    __shared__ float stk[FB_G][STK_][F_];
    __shared__ float hh[FB_G][H_];
    __shared__ float boxtmp[FB_G][MAXB_][BOX_];
    __shared__ float symtmp[FB_G][MAXSY_][S_];
    const int t = threadIdx.x, b0 = blockIdx.x * FB_G;
    for (int idx = t; idx < FB_G*F_; idx += 1024) {
        int g = idx >> 9, k = idx & (F_-1);
        stk[g][0][k] = inputStacks[(size_t)(b0+g)*F_ + k];
    }
    for (int idx = t; idx < FB_G*H_; idx += 1024) hh[idx>>10][idx&(H_-1)] = 0.f;
    int sp[FB_G], bc[FB_G], sc[FB_G];
#pragma unroll
    for (int g = 0; g < FB_G; ++g) { sp[g]=1; bc[g]=0; sc[g]=0; }
    __syncthreads();
    for (int step = 0; step < L_; ++step) {
        int op[FB_G], ti[FB_G], ri[FB_G]; bool a1=false,a2=false,a0=false;
#pragma unroll
        for (int g = 0; g < FB_G; ++g) {
            op[g] = ops[(size_t)(b0+g)*L_ + (L_-1-step)];
            int tt = sp[g]-1; tt = tt<0?0:(tt>STK_-1?STK_-1:tt); ti[g]=tt;
            int rr = sp[g]; ri[g] = rr>STK_-1?STK_-1:rr;
            a1 |= (op[g]==1); a2 |= (op[g]==2); a0 |= (op[g]==0);
        }
        const float *x0=stk[0][ti[0]], *x1=stk[1][ti[1]], *x2=stk[2][ti[2]], *x3=stk[3][ti[3]];
        if (a1) {
            float r0,r1,r2,r3; fdot4(Wd+(size_t)t*F_, x0,x1,x2,x3, F_/4, r0,r1,r2,r3);
            float bb = bd[t];
            if (op[0]==1) hh[0][t]=tanhf(r0+bb); if (op[1]==1) hh[1][t]=tanhf(r1+bb);
            if (op[2]==1) hh[2][t]=tanhf(r2+bb); if (op[3]==1) hh[3][t]=tanhf(r3+bb);
        }
        if (a2) {
            float r0,r1,r2,r3; fdot4(Wsd+(size_t)t*F_, x0,x1,x2,x3, F_/4, r0,r1,r2,r3);
            float bb = bsd[t];
            if (op[0]==2) hh[0][t]=tanhf(r0+bb); if (op[1]==2) hh[1][t]=tanhf(r1+bb);
            if (op[2]==2) hh[2][t]=tanhf(r2+bb); if (op[3]==2) hh[3][t]=tanhf(r3+bb);
        }
        if (a0 && t < FB_G*BOX_) {
            int g = t / BOX_, cc = t - g*BOX_;
            if (op[g]==0) {
                float acc = fdot1(Wbox+(size_t)cc*F_, stk[g][ti[g]], F_/4);
                boxtmp[g][bc[g]][cc] = tanhf(acc + bbox[cc]);
            }
        }
        __syncthreads();
        if (a1) {
            if (t < F_) {
                float r0,r1,r2,r3; fdot4(Wl+(size_t)t*H_, hh[0],hh[1],hh[2],hh[3], H_/4, r0,r1,r2,r3);
                float bb = bl[t];
                if (op[0]==1) stk[0][ti[0]][t]=tanhf(r0+bb); if (op[1]==1) stk[1][ti[1]][t]=tanhf(r1+bb);
                if (op[2]==1) stk[2][ti[2]][t]=tanhf(r2+bb); if (op[3]==1) stk[3][ti[3]][t]=tanhf(r3+bb);
            } else {
                int m = t - F_;
                float r0,r1,r2,r3; fdot4(Wr+(size_t)m*H_, hh[0],hh[1],hh[2],hh[3], H_/4, r0,r1,r2,r3);
                float bb = br[m];
                if (op[0]==1) stk[0][ri[0]][m]=tanhf(r0+bb); if (op[1]==1) stk[1][ri[1]][m]=tanhf(r1+bb);
                if (op[2]==1) stk[2][ri[2]][m]=tanhf(r2+bb); if (op[3]==1) stk[3][ri[3]][m]=tanhf(r3+bb);
            }
        }
        if (a2) {
            if (t < F_) {
                float r0,r1,r2,r3; fdot4(Wsf+(size_t)t*H_, hh[0],hh[1],hh[2],hh[3], H_/4, r0,r1,r2,r3);
                float bb = bsf[t];
                if (op[0]==2) stk[0][ti[0]][t]=tanhf(r0+bb); if (op[1]==2) stk[1][ti[1]][t]=tanhf(r1+bb);
                if (op[2]==2) stk[2][ti[2]][t]=tanhf(r2+bb); if (op[3]==2) stk[3][ti[3]][t]=tanhf(r3+bb);
            } else if (t < F_ + FB_G*S_) {
                int idx = t - F_, g = idx >> 3, cc = idx & 7;
                if (op[g]==2) {
                    float acc = fdot1(Wss+(size_t)cc*H_, hh[g], H_/4);
                    symtmp[g][sc[g]][cc] = tanhf(acc + bss[cc]);
                }
            }
        }
        __syncthreads();
#pragma unroll
        for (int g = 0; g < FB_G; ++g) {
            if (op[g]==1) sp[g]++;
            else if (op[g]==2) sc[g]++;
            else { bc[g]++; sp[g]--; }
        }
    }
#pragma unroll
    for (int g = 0; g < FB_G; ++g) {
        int b = b0 + g;
        float* ob = out + (size_t)b * MAXB_ * BOX_;
        for (int idx = t; idx < MAXB_*BOX_; idx += 1024) {
            int jj = idx / BOX_, cc = idx - jj*BOX_;
            int e = bc[g] - 1 - jj;
            ob[idx] = (e >= 0) ? boxtmp[g][e][cc] : 0.f;
        }
        float* os = out + (size_t)B_*MAXB_*BOX_ + (size_t)b * MAXSY_ * S_;
        for (int idx = t; idx < MAXSY_*S_; idx += 1024) {
            int jj = idx >> 3, cc = idx & 7;
            int e = sc[g] - 1 - jj;
            os[idx] = (e >= 0) ? symtmp[g][e][cc] : 0.f;
        }
    }
}

// ---------------- launcher ----------------
extern "C" void kernel_launch(void* const* d_in, const int* in_sizes, int n_in,
                              void* d_out, int out_size, void* d_ws, size_t ws_size,
                              hipStream_t stream) {
    (void)in_sizes; (void)n_in;
    const float* X    = (const float*)d_in[0];
    const int*   ops  = (const int*)d_in[1];
    const float* Wd   = (const float*)d_in[2];  const float* bd   = (const float*)d_in[3];
    const float* Wl   = (const float*)d_in[4];  const float* bl   = (const float*)d_in[5];
    const float* Wr   = (const float*)d_in[6];  const float* br   = (const float*)d_in[7];
    const float* Wsd  = (const float*)d_in[8];  const float* bsd  = (const float*)d_in[9];
    const float* Wsf  = (const float*)d_in[10]; const float* bsf  = (const float*)d_in[11];
    const float* Wss  = (const float*)d_in[12]; const float* bss  = (const float*)d_in[13];
    const float* Wbox = (const float*)d_in[14]; const float* bbox = (const float*)d_in[15];
    float* out = (float*)d_out;

    if (ws_size < WS_NEED) {
        grass_fallback<<<dim3(B_/FB_G), dim3(1024), 0, stream>>>(
            X, ops, Wd, bd, Wl, bl, Wr, br, Wsd, bsd, Wsf, bsf, Wss, bss, Wbox, bbox, out);
        return;
    }
    char* ws = (char*)d_ws;
    hipMemsetAsync(d_out, 0, (size_t)out_size * sizeof(float), stream);  // zero-pad slots
    hipMemsetAsync(ws, 0, 8192, stream);   // barriers + flags + xcd slots
    grass_prep<<<dim3(512), dim3(256), 0, stream>>>(X, ops, Wd, Wl, Wr, Wsd, Wsf, Wss, Wbox, ws);
    grass_pipe<<<dim3(512), dim3(256), 0, stream>>>(bd, bl, br, bsd, bsf, bss, bbox, ws, out);
    grass_legacy<<<dim3(256), dim3(256), 0, stream>>>(ops, bd, bl, br, bsd, bsf, bss, bbox, ws, out);
}